// Round 7
// baseline (454.463 us; speedup 1.0000x reference)
//
#include <hip/hip_runtime.h>
#include <hip/hip_bf16.h>
#include <math.h>

#define LYR 8
#define SEQ 4096
#define DIM 2048
#define NH 16
#define HD 128
#define NQ 32
#define NKV 256   // KVH*HD
#define NQE 2048  // H*HD

typedef __attribute__((ext_vector_type(8))) short short8;
typedef __attribute__((ext_vector_type(4))) float f32x4;

// workspace layout (float units)
#define WS_IRQ   0                        // 256
#define WS_ABLOB 256                      // 524288 floats = 1048576 shorts (A-frag blob for Q)
#define WS_COS   524544                   // 524288
#define WS_SIN   1048832                  // 524288
#define WS_QBUF  1573120                  // 524288  summed Q fp32 [l][q][2048]
#define WS_PART  2097408                  // 2097152 partials [ks4][l][q][2048]
#define WS_W2    4194560                  // 4194304 floats = 8388608 shorts (16MB)
#define WS_KBLOB 8388864                  // 8388608 floats = 16777216 shorts (32MB)
#define WS_QBLOB 16777472                 // 524288 floats = 1048576 shorts
// end 17301760 floats ~ 69.2 MB

__device__ __forceinline__ short f2bf(float x) {
  __hip_bfloat16 h = __float2bfloat16(x);
  return *(short*)&h;
}
__device__ __forceinline__ float bf2f(short s) {
  unsigned u = ((unsigned)(unsigned short)s) << 16;
  return __uint_as_float(u);
}

#define GLOAD16(srcp, dstp) \
  __builtin_amdgcn_global_load_lds( \
      (const __attribute__((address_space(1))) unsigned int*)(srcp), \
      (__attribute__((address_space(3))) unsigned int*)(dstp), 16, 0, 0)

// raw barrier: drain LDS ops only; leave global loads in flight across the barrier
#define RBAR() asm volatile("s_waitcnt lgkmcnt(0)\n\ts_barrier" ::: "memory")

// ---------------- prep: W' = ln_w*k_w -> frag-lane-linear bf16 hi/lo blob ----------------
__global__ __launch_bounds__(256) void prep_kernel(
    const float* __restrict__ ln_w, const float* __restrict__ k_w,
    short* __restrict__ W2) {
  int kb = blockIdx.x, l = blockIdx.y, t = threadIdx.x;
  const float* kwl = k_w + (size_t)l * DIM * NKV;
  const float* lnl = ln_w + l * DIM;
  short* blob = W2 + (size_t)(l * 64 + kb) * 16384;
  #pragma unroll
  for (int i = 0; i < 4; ++i) {
    int p = t + i * 256;
    int fi = p >> 6, lane = p & 63;
    int n = fi * 16 + (lane & 15);
    int k0 = kb * 32 + (lane >> 4) * 8;
    short hi8[8], lo8[8];
    #pragma unroll
    for (int e = 0; e < 8; ++e) {
      float v = lnl[k0 + e] * kwl[(size_t)(k0 + e) * NKV + n];
      short h = f2bf(v);
      hi8[e] = h;
      lo8[e] = f2bf(v - bf2f(h));
    }
    *(short8*)(blob + p * 8) = *(short8*)hi8;
    *(short8*)(blob + 8192 + p * 8) = *(short8*)lo8;
  }
}

// ---------------- rmsq: inv_rms for the 32 q rows ----------------
__global__ __launch_bounds__(256) void rmsq_kernel(const float* __restrict__ hs,
                                                   const int* __restrict__ q_idx,
                                                   float* __restrict__ irq) {
  int qi = blockIdx.x, l = blockIdx.y, t = threadIdx.x;
  int s = q_idx[qi];
  const float* row = hs + ((size_t)l * SEQ + s) * DIM;
  float4 v0 = *(const float4*)(row + t * 4);
  float4 v1 = *(const float4*)(row + t * 4 + 1024);
  float acc = v0.x*v0.x + v0.y*v0.y + v0.z*v0.z + v0.w*v0.w
            + v1.x*v1.x + v1.y*v1.y + v1.z*v1.z + v1.w*v1.w;
  #pragma unroll
  for (int off = 32; off >= 1; off >>= 1) acc += __shfl_down(acc, off);
  __shared__ float red[4];
  if ((t & 63) == 0) red[t >> 6] = acc;
  __syncthreads();
  if (t == 0) {
    float tot = red[0] + red[1] + red[2] + red[3];
    irq[l * NQ + qi] = rsqrtf(tot / (float)DIM + 1e-6f);
  }
}

// ---------------- cossin: mrope tables [S][HD] ----------------
__global__ void cossin_kernel(const int* __restrict__ pos_ids,
                              float* __restrict__ cost, float* __restrict__ sint) {
  int idx = blockIdx.x * 256 + threadIdx.x;
  int s = idx >> 7, d = idx & 127;
  int t = (d < 32) ? 0 : (d < 80 ? 1 : 2);
  int j = d & 63;
  double invf = pow(1000000.0, -(double)j / 64.0);
  double ph = (double)pos_ids[t * SEQ + s] * invf;
  cost[idx] = (float)cos(ph);
  sint[idx] = (float)sin(ph);
}

// ---------------- xqt: build A-frag blob for Q proj ----------------
__global__ __launch_bounds__(256) void xqt_kernel(
    const float* __restrict__ hs, const float* __restrict__ ln_w,
    const int* __restrict__ q_idx, const float* __restrict__ irq,
    short* __restrict__ Ablob) {
  __shared__ int qix[32];
  __shared__ float qir[32];
  int l = blockIdx.x, t = threadIdx.x;
  if (t < 32) { qix[t] = q_idx[t]; qir[t] = irq[l * NQ + t]; }
  __syncthreads();
  int lane = t & 63, g4 = t >> 6;
  short* base = Ablob + (size_t)l * 131072;
  int row = lane & 15, kgl = lane >> 4;
  for (int i = 0; i < 64; ++i) {
    int group = g4 * 64 + i;                 // (kb, half, mf)
    int kb = group >> 2, half = (group >> 1) & 1, mf = group & 1;
    int r = row + mf * 16;
    int k0 = kb * 32 + kgl * 8;
    const float* src = hs + ((size_t)l * SEQ + qix[r]) * DIM + k0;
    const float* lnp = ln_w + l * DIM + k0;
    float ir = qir[r];
    float4 v0 = *(const float4*)src;
    float4 v1 = *(const float4*)(src + 4);
    float4 w0 = *(const float4*)lnp;
    float4 w1 = *(const float4*)(lnp + 4);
    float av[8] = {v0.x*w0.x, v0.y*w0.y, v0.z*w0.z, v0.w*w0.w,
                   v1.x*w1.x, v1.y*w1.y, v1.z*w1.z, v1.w*w1.w};
    short o8[8];
    #pragma unroll
    for (int e = 0; e < 8; ++e) {
      float v = av[e] * ir;
      short h = f2bf(v);
      o8[e] = half ? f2bf(v - bf2f(h)) : h;
    }
    *(short8*)(base + group * 512 + lane * 8) = *(short8*)o8;
  }
}

// ---------------- kgemm: K proj bf16x3 MFMA, intra-block K-split (8 waves) ----------------
// BM=64 BN=256, 512 thr = 8 waves: group g = w>>2 does K-half g (32 steps of BK=32).
// A via LDS (per-group 16KB dbuf), B direct global->VGPR frag loads (reg ping-pong).
// Epilogue: combine group partials in LDS, RMSNorm+bias+RoPE, blob write.
__global__ __launch_bounds__(512, 4) void kgemm_kernel(
    const float* __restrict__ hs, const short* __restrict__ W2,
    const float* __restrict__ k_b, const float* __restrict__ cost,
    const float* __restrict__ sint, short* __restrict__ Kblob) {
  __shared__ __align__(1024) char SM[67584];
  // loop:    [0,16384)=A group0 dbuf, [16384,32768)=A group1 dbuf
  // epilogue: X=[64][260] fp32 at [0,66560); sqpart [66560,67072); irs [67072,67328)

  int t = threadIdx.x;
  int fid = blockIdx.x;
  int l = fid & 7, sb = fid >> 3;
  int s0 = sb * 64;
  int lane = t & 63, w = t >> 6;
  int wn = w & 3, g = w >> 2;
  int fr = lane & 15, kg = lane >> 4;
  int tg = t & 255;
  int arow = tg >> 2, akg = tg & 3;

  const float* hrow = hs + ((size_t)l * SEQ + s0 + arow) * DIM + g * 1024 + akg * 8;
  const char* wbase = (const char*)(W2 + (size_t)l * 64 * 16384);
  const char* wfrag = wbase + (size_t)g * 1048576 + wn * 1024 + lane * 16;

  int abase = g * 16384;
  int amf = arow >> 4;
  int awoff = abase + amf * 1024 + (((akg * 16 + (arow & 15)) * 16) ^ (akg << 5));
  int aroff = abase + ((lane * 16) ^ ((lane >> 4) << 5));

  f32x4 acc[4][4];
  #pragma unroll
  for (int mf = 0; mf < 4; ++mf)
    #pragma unroll
    for (int nf = 0; nf < 4; ++nf) acc[mf][nf] = (f32x4){0.f, 0.f, 0.f, 0.f};
  float sq = 0.f;
  short8 B0h[4], B0l[4], B1h[4], B1l[4];

  // prologue: B(0) -> B0 regs; A(0) -> cvt+write buf0
  {
    #pragma unroll
    for (int nf = 0; nf < 4; ++nf) {
      B0h[nf] = *(const short8*)(wfrag + nf * 4096);
      B0l[nf] = *(const short8*)(wfrag + nf * 4096 + 16384);
    }
    float4 a0 = *(const float4*)(hrow);
    float4 a1 = *(const float4*)(hrow + 4);
    float av[8] = {a0.x, a0.y, a0.z, a0.w, a1.x, a1.y, a1.z, a1.w};
    short hi8[8], lo8[8];
    #pragma unroll
    for (int e = 0; e < 8; ++e) {
      sq += av[e] * av[e];
      short h = f2bf(av[e]);
      hi8[e] = h;
      lo8[e] = f2bf(av[e] - bf2f(h));
    }
    *(short8*)(SM + awoff) = *(short8*)hi8;
    *(short8*)(SM + 4096 + awoff) = *(short8*)lo8;
  }
  RBAR();

#define KSTEP(KB, UBH, UBL, PBH, PBL) do { \
    int buf_ = (KB) & 1; \
    const char* asb_ = SM + buf_ * 8192; \
    float4 a0_, a1_; \
    if ((KB) < 31) { \
      a0_ = *(const float4*)(hrow + ((KB) + 1) * 32); \
      a1_ = *(const float4*)(hrow + ((KB) + 1) * 32 + 4); \
      const char* bsrc_ = wfrag + (size_t)((KB) + 1) * 32768; \
      _Pragma("unroll") \
      for (int nf = 0; nf < 4; ++nf) { \
        PBH[nf] = *(const short8*)(bsrc_ + nf * 4096); \
        PBL[nf] = *(const short8*)(bsrc_ + nf * 4096 + 16384); \
      } \
    } \
    short8 ah_[4], al_[4]; \
    _Pragma("unroll") \
    for (int mf = 0; mf < 4; ++mf) { \
      ah_[mf] = *(const short8*)(asb_ + mf * 1024 + aroff); \
      al_[mf] = *(const short8*)(asb_ + 4096 + mf * 1024 + aroff); \
    } \
    _Pragma("unroll") \
    for (int nf = 0; nf < 4; ++nf) { \
      _Pragma("unroll") \
      for (int mf = 0; mf < 4; ++mf) { \
        acc[mf][nf] = __builtin_amdgcn_mfma_f32_16x16x32_bf16(ah_[mf], UBH[nf], acc[mf][nf], 0, 0, 0); \
        acc[mf][nf] = __builtin_amdgcn_mfma_f32_16x16x32_bf16(ah_[mf], UBL[nf], acc[mf][nf], 0, 0, 0); \
        acc[mf][nf] = __builtin_amdgcn_mfma_f32_16x16x32_bf16(al_[mf], UBH[nf], acc[mf][nf], 0, 0, 0); \
      } \
    } \
    if ((KB) < 31) { \
      char* asn_ = SM + (buf_ ^ 1) * 8192; \
      float av_[8] = {a0_.x, a0_.y, a0_.z, a0_.w, a1_.x, a1_.y, a1_.z, a1_.w}; \
      short hi8_[8], lo8_[8]; \
      _Pragma("unroll") \
      for (int e = 0; e < 8; ++e) { \
        sq += av_[e] * av_[e]; \
        short h_ = f2bf(av_[e]); \
        hi8_[e] = h_; \
        lo8_[e] = f2bf(av_[e] - bf2f(h_)); \
      } \
      *(short8*)(asn_ + awoff) = *(short8*)hi8_; \
      *(short8*)(asn_ + 4096 + awoff) = *(short8*)lo8_; \
    } \
    RBAR(); \
  } while (0)

  for (int kb2 = 0; kb2 < 16; ++kb2) {
    KSTEP(2 * kb2,     B0h, B0l, B1h, B1l);
    KSTEP(2 * kb2 + 1, B1h, B1l, B0h, B0l);
  }
#undef KSTEP

  // ---- epilogue ----
  // per-(group,row) sumsq partial: lanes t, t^1, t^2 share arow (differ akg)
  sq += __shfl_xor(sq, 1);
  sq += __shfl_xor(sq, 2);
  float* sqpart = (float*)(SM + 66560);
  if ((t & 3) == 0) sqpart[g * 64 + arow] = sq;

  // group-1 waves park their acc partials in X[64][260]
  float* X = (float*)SM;
  int j = wn * 16 + fr;
  if (g == 1) {
    #pragma unroll
    for (int mf = 0; mf < 4; ++mf) {
      #pragma unroll
      for (int r = 0; r < 4; ++r) {
        int row = mf * 16 + kg * 4 + r;
        #pragma unroll
        for (int nf = 0; nf < 4; ++nf)
          X[row * 260 + j + nf * 64] = acc[mf][nf][r];
      }
    }
  }
  __syncthreads();

  float* irs = (float*)(SM + 67072);
  if (t < 64)
    irs[t] = rsqrtf((sqpart[t] + sqpart[64 + t]) / (float)DIM + 1e-6f);
  __syncthreads();

  if (g == 0) {
    float bias0 = k_b[l * NKV + j];
    float bias1 = k_b[l * NKV + j + 64];
    float bias2 = k_b[l * NKV + j + 128];
    float bias3 = k_b[l * NKV + j + 192];
    #pragma unroll
    for (int mf = 0; mf < 4; ++mf) {
      #pragma unroll
      for (int r = 0; r < 4; ++r) {
        int row = mf * 16 + kg * 4 + r;
        int s = s0 + row;
        float ir = irs[row];
        float p0 = X[row * 260 + j]       + acc[mf][0][r];
        float p1 = X[row * 260 + j + 64]  + acc[mf][1][r];
        float p2 = X[row * 260 + j + 128] + acc[mf][2][r];
        float p3 = X[row * 260 + j + 192] + acc[mf][3][r];
        float v0 = p0 * ir + bias0;
        float v1 = p1 * ir + bias1;
        float v2 = p2 * ir + bias2;
        float v3 = p3 * ir + bias3;
        float cj = cost[s * HD + j], sj = sint[s * HD + j];
        float cj2 = cost[s * HD + j + 64], sj2 = sint[s * HD + j + 64];
        X[row * 260 + j]       = v0 * cj - v1 * sj;
        X[row * 260 + j + 64]  = v1 * cj2 + v0 * sj2;
        X[row * 260 + j + 128] = v2 * cj - v3 * sj;
        X[row * 260 + j + 192] = v3 * cj2 + v2 * sj2;
      }
    }
  }
  __syncthreads();

  // blob write: 2048 chunks of short8 pairs, 512 threads x 4 iters
  int kc = sb >> 1, fb = (sb & 1) * 4;
  #pragma unroll
  for (int i = 0; i < 4; ++i) {
    int c = t + i * 512;
    int lc = c & 63, fl = (c >> 6) & 3, ts = (c >> 8) & 3, kv = c >> 10;
    int key = fl * 16 + (lc & 15);
    int d0 = kv * 128 + ts * 32 + (lc >> 4) * 8;
    float4 x0 = *(const float4*)(X + key * 260 + d0);
    float4 x1 = *(const float4*)(X + key * 260 + d0 + 4);
    float av[8] = {x0.x, x0.y, x0.z, x0.w, x1.x, x1.y, x1.z, x1.w};
    short hi8[8], lo8[8];
    #pragma unroll
    for (int e = 0; e < 8; ++e) {
      short h = f2bf(av[e]);
      hi8[e] = h;
      lo8[e] = f2bf(av[e] - bf2f(h));
    }
    short* bb = Kblob + (size_t)((l * 2 + kv) * 32 + kc) * 32768
              + (size_t)((ts * 2 + 0) * 8 + fb + fl) * 512 + lc * 8;
    *(short8*)bb = *(short8*)hi8;
    *(short8*)(bb + 4096) = *(short8*)lo8;
  }
}

// ---------------- qgemm: Q = xq . q_w via bf16x3 MFMA, q_w streamed fp32 ----------------
__global__ __launch_bounds__(512) void qgemm_kernel(
    const float* __restrict__ q_w, const short* __restrict__ Ablob,
    float* __restrict__ part) {
  __shared__ __align__(1024) char SM[131072];
  int t = threadIdx.x;
  int nc = blockIdx.x, ks = blockIdx.y, l = blockIdx.z;
  int lane = t & 63, w = t >> 6;
  int fr = lane & 15, kg = lane >> 4;
  const char* abase = (const char*)(Ablob + (size_t)l * 131072 + (size_t)ks * 32768);
  const float* qwl = q_w + (size_t)l * DIM * NQE;

  #pragma unroll
  for (int c = 0; c < 8; ++c) {
    int chunk = w * 8 + c;
    GLOAD16(abase + chunk * 1024 + lane * 16, SM + chunk * 1024);
  }
  #pragma unroll
  for (int c = 0; c < 4; ++c) {
    int r = w * 4 + c;
    GLOAD16((const char*)(qwl + (size_t)(ks * 512 + r) * NQE + nc * 256) + lane * 16,
            SM + 65536 + r * 1024 + lane * 16);
  }
  f32x4 acc[2][2];
  #pragma unroll
  for (int mf = 0; mf < 2; ++mf)
    #pragma unroll
    for (int nf = 0; nf < 2; ++nf) acc[mf][nf] = (f32x4){0.f, 0.f, 0.f, 0.f};
  __syncthreads();

  for (int ts = 0; ts < 16; ++ts) {
    int buf = ts & 1;
    if (ts < 15) {
      #pragma unroll
      for (int c = 0; c < 4; ++c) {
        int r = w * 4 + c;
        GLOAD16((const char*)(qwl + (size_t)(ks * 512 + (ts + 1) * 32 + r) * NQE + nc * 256) + lane * 16,
                SM + 65536 + (buf ^ 1) * 32768 + r * 1024 + lane * 16);
      }
    }
    short8 ah[2], al[2];
    #pragma unroll
    for (int mf = 0; mf < 2; ++mf) {
      ah[mf] = *(const short8*)(SM + ts * 4096 + mf * 1024 + lane * 16);
      al[mf] = *(const short8*)(SM + ts * 4096 + 2048 + mf * 1024 + lane * 16);
    }
    const float* bt = (const float*)(SM + 65536 + buf * 32768);
    #pragma unroll
    for (int nf = 0; nf < 2; ++nf) {
      int c = w * 32 + nf * 16 + fr;
      short bh8[8], bl8[8];
      #pragma unroll
      for (int e = 0; e < 8; ++e) {
        float v = bt[(kg * 8 + e) * 256 + c];
        short h = f2bf(v);
        bh8[e] = h;
        bl8[e] = f2bf(v - bf2f(h));
      }
      short8 bh = *(short8*)bh8, bl = *(short8*)bl8;
      #pragma unroll
      for (int mf = 0; mf < 2; ++mf) {
        acc[mf][nf] = __builtin_amdgcn_mfma_f32_16x16x32_bf16(ah[mf], bh, acc[mf][nf], 0, 0, 0);
        acc[mf][nf] = __builtin_amdgcn_mfma_f32_16x16x32_bf16(ah[mf], bl, acc[mf][nf], 0, 0, 0);
        acc[mf][nf] = __builtin_amdgcn_mfma_f32_16x16x32_bf16(al[mf], bh, acc[mf][nf], 0, 0, 0);
      }
    }
    __syncthreads();
  }

  #pragma unroll
  for (int mf = 0; mf < 2; ++mf) {
    #pragma unroll
    for (int r = 0; r < 4; ++r) {
      int row = mf * 16 + kg * 4 + r;
      float* prow = part + ((size_t)((ks * LYR + l) * NQ + row)) * NQE + nc * 256;
      #pragma unroll
      for (int nf = 0; nf < 2; ++nf) {
        int col = w * 32 + nf * 16 + fr;
        prow[col] = acc[mf][nf][r];
      }
    }
  }
}

// ---------------- qred: sum 4 k-split partials + bias -> Qbuf ----------------
__global__ __launch_bounds__(256) void qred_kernel(
    const float* __restrict__ part, const float* __restrict__ q_b,
    float* __restrict__ Qbuf) {
  int idx = blockIdx.x * 256 + threadIdx.x;
  int n = idx & 2047, q = (idx >> 11) & 31, l = idx >> 16;
  float v = q_b[l * NQE + n];
  #pragma unroll
  for (int ks = 0; ks < 4; ++ks)
    v += part[((size_t)((ks * LYR + l) * NQ + q)) * NQE + n];
  Qbuf[((size_t)l * NQ + q) * NQE + n] = v;
}

// ---------------- qpack: rope Q + split to frag-lane-linear blob ----------------
__global__ __launch_bounds__(256) void qpack_kernel(
    const float* __restrict__ Qbuf, const float* __restrict__ cost,
    const float* __restrict__ sint, const int* __restrict__ q_idx,
    short* __restrict__ Qblob) {
  int kv = blockIdx.x, l = blockIdx.y, t = threadIdx.x;
  short* blob = Qblob + (size_t)(l * 2 + kv) * 65536;
  #pragma unroll
  for (int i = 0; i < 16; ++i) {
    int p = t + i * 256;
    int ts = p >> 10, f = (p >> 6) & 15, lane = p & 63;
    int row = f * 16 + (lane & 15);
    int hh = row >> 5, q = row & 31;
    int h = kv * 8 + hh;
    int d0 = ts * 32 + (lane >> 4) * 8;
    int s = q_idx[q];
    const float* qrow = Qbuf + ((size_t)l * NQ + q) * NQE + h * HD;
    const float* ct = cost + s * HD;
    const float* st = sint + s * HD;
    short hi8[8], lo8[8];
    #pragma unroll
    for (int e = 0; e < 8; ++e) {
      int d = d0 + e;
      float x = qrow[d];
      float xp = qrow[d ^ 64];
      float v = (d < 64) ? (x * ct[d] - xp * st[d]) : (x * ct[d] + xp * st[d]);
      short h2 = f2bf(v);
      hi8[e] = h2;
      lo8[e] = f2bf(v - bf2f(h2));
    }
    *(short8*)(blob + ((ts * 2 + 0) * 16 + f) * 512 + lane * 8) = *(short8*)hi8;
    *(short8*)(blob + ((ts * 2 + 1) * 16 + f) * 512 + lane * 8) = *(short8*)lo8;
  }
}

// ---------------- scores: bf16x3 MFMA, M=256 (8 heads x 32 q) x 128 keys ----------------
__global__ __launch_bounds__(512) void scores_kernel(
    const short* __restrict__ Qblob, const short* __restrict__ Kblob,
    const int* __restrict__ q_idx, float* __restrict__ out) {
  __shared__ short Qs[2][16384];
  __shared__ short Ks[2][8192];
  __shared__ int qiv[32];
  int t = threadIdx.x;
  int kc = blockIdx.x, kv = blockIdx.y, l = blockIdx.z;
  int lane = t & 63, w = t >> 6;
  int wm = w >> 1, wn = w & 1;
  if (t < 32) qiv[t] = q_idx[t];
  const char* qsrc = (const char*)(Qblob + (size_t)(l * 2 + kv) * 65536);
  const char* ksrc = (const char*)(Kblob + (size_t)((l * 2 + kv) * 32 + kc) * 32768);
  #pragma unroll
  for (int c = 0; c < 4; ++c) {
    int off = (w * 4 + c) * 1024;
    GLOAD16(qsrc + off + lane * 16, (char*)Qs[0] + off);
  }
  #pragma unroll
  for (int c = 0; c < 2; ++c) {
    int off = (w * 2 + c) * 1024;
    GLOAD16(ksrc + off + lane * 16, (char*)Ks[0] + off);
  }
  f32x4 acc[4][4];
  #pragma unroll
  for (int mf = 0; mf < 4; ++mf)
    #pragma unroll
    for (int nf = 0; nf < 4; ++nf) acc[mf][nf] = (f32x4){0.f, 0.f, 0.f, 0.f};
  __syncthreads();
  for (int ts = 0; ts < 4; ++ts) {
    int buf = ts & 1;
    if (ts < 3) {
      const char* qs = qsrc + (ts + 1) * 32768;
      const char* ks = ksrc + (ts + 1) * 16384;
      #pragma unroll
      for (int c = 0; c < 4; ++c) {
        int off = (w * 4 + c) * 1024;
        GLOAD16(qs + off + lane * 16, (char*)Qs[(ts + 1) & 1] + off);
      }
      #pragma unroll
      for (int c = 0; c < 2; ++c) {
        int off = (w * 2 + c) * 1024;
        GLOAD16(ks + off + lane * 16, (char*)Ks[(ts + 1) & 1] + off);
      }
    }
    short8 ah[4], al[4];
    #pragma unroll
    for (int mf = 0; mf < 4; ++mf) {
      int f = wm * 4 + mf;
      ah[mf] = *(const short8*)(Qs[buf] + f * 512 + lane * 8);
      al[mf] = *(const short8*)(Qs[buf] + 8192 + f * 512 + lane * 8);
    }
    #pragma unroll
    for (int nf = 0; nf < 4; ++nf) {
      int f = wn * 4 + nf;
      short8 bh = *(const short8*)(Ks[buf] + f * 512 + lane * 8);
      short8 bl = *(const short8*)(Ks[buf] + 4096 + f * 512 + lane * 8);
      #pragma unroll
      for (int mf = 0; mf < 4; ++mf) {
        acc[mf][nf] = __builtin_amdgcn_mfma_f32_16x16x32_bf16(ah[mf], bh, acc[mf][nf], 0, 0, 0);
        acc[mf][nf] = __builtin_amdgcn_mfma_f32_16x16x32_bf16(ah[mf], bl, acc[mf][nf], 0, 0, 0);
        acc[mf][nf] = __builtin_amdgcn_mfma_f32_16x16x32_bf16(al[mf], bh, acc[mf][nf], 0, 0, 0);
      }
    }
    __syncthreads();
  }
  const float scale = 0.088388347648318447f;
  #pragma unroll
  for (int mf = 0; mf < 4; ++mf) {
    #pragma unroll
    for (int r = 0; r < 4; ++r) {
      int rr = wm * 64 + mf * 16 + (lane >> 4) * 4 + r;
      int hh = rr >> 5, q = rr & 31;
      int qv = qiv[q];
      float* orow = out + (((size_t)(l * NH + kv * 8 + hh)) * NQ + q) * SEQ;
      #pragma unroll
      for (int nf = 0; nf < 4; ++nf) {
        int key = kc * 128 + (wn * 4 + nf) * 16 + (lane & 15);
        orow[key] = (key > qv) ? -1e9f : acc[mf][nf][r] * scale;
      }
    }
  }
}

// ---------------- softmax over S ----------------
__global__ __launch_bounds__(256) void softmax_kernel(float* __restrict__ out) {
  size_t row = blockIdx.x;
  float* p = out + row * SEQ;
  int t = threadIdx.x;
  float4 v[4];
  float mx = -1e30f;
  #pragma unroll
  for (int i = 0; i < 4; ++i) {
    v[i] = *(const float4*)(p + t * 4 + i * 1024);
    mx = fmaxf(mx, fmaxf(fmaxf(v[i].x, v[i].y), fmaxf(v[i].z, v[i].w)));
  }
  #pragma unroll
  for (int off = 32; off >= 1; off >>= 1) mx = fmaxf(mx, __shfl_xor(mx, off));
  __shared__ float red[4];
  if ((t & 63) == 0) red[t >> 6] = mx;
  __syncthreads();
  mx = fmaxf(fmaxf(red[0], red[1]), fmaxf(red[2], red[3]));
  __syncthreads();
  float sum = 0.f;
  #pragma unroll
  for (int i = 0; i < 4; ++i) {
    v[i].x = __expf(v[i].x - mx); v[i].y = __expf(v[i].y - mx);
    v[i].z = __expf(v[i].z - mx); v[i].w = __expf(v[i].w - mx);
    sum += v[i].x + v[i].y + v[i].z + v[i].w;
  }
  #pragma unroll
  for (int off = 32; off >= 1; off >>= 1) sum += __shfl_xor(sum, off);
  if ((t & 63) == 0) red[t >> 6] = sum;
  __syncthreads();
  sum = red[0] + red[1] + red[2] + red[3];
  float inv = 1.f / sum;
  #pragma unroll
  for (int i = 0; i < 4; ++i) {
    v[i].x *= inv; v[i].y *= inv; v[i].z *= inv; v[i].w *= inv;
    *(float4*)(p + t * 4 + i * 1024) = v[i];
  }
}

extern "C" void kernel_launch(void* const* d_in, const int* in_sizes, int n_in,
                              void* d_out, int out_size, void* d_ws, size_t ws_size,
                              hipStream_t stream) {
  const float* hs   = (const float*)d_in[0];
  const float* ln_w = (const float*)d_in[1];
  const float* q_w  = (const float*)d_in[2];
  const float* q_b  = (const float*)d_in[3];
  const float* k_w  = (const float*)d_in[4];
  const float* k_b  = (const float*)d_in[5];
  const int* pos    = (const int*)d_in[6];
  const int* qidx   = (const int*)d_in[7];
  float* out = (float*)d_out;
  float* ws = (float*)d_ws;
  float* irq   = ws + WS_IRQ;
  short* Ablob = (short*)(ws + WS_ABLOB);
  float* cost  = ws + WS_COS;
  float* sint  = ws + WS_SIN;
  float* Qbuf  = ws + WS_QBUF;
  float* part  = ws + WS_PART;
  short* W2    = (short*)(ws + WS_W2);
  short* Kblob = (short*)(ws + WS_KBLOB);
  short* Qblob = (short*)(ws + WS_QBLOB);

  prep_kernel<<<dim3(64, LYR), 256, 0, stream>>>(ln_w, k_w, W2);
  rmsq_kernel<<<dim3(NQ, LYR), 256, 0, stream>>>(hs, qidx, irq);
  cossin_kernel<<<(SEQ * HD) / 256, 256, 0, stream>>>(pos, cost, sint);
  xqt_kernel<<<LYR, 256, 0, stream>>>(hs, ln_w, qidx, irq, Ablob);
  kgemm_kernel<<<512, 512, 0, stream>>>(hs, W2, k_b, cost, sint, Kblob);
  qgemm_kernel<<<dim3(8, 4, LYR), 512, 0, stream>>>(q_w, Ablob, part);
  qred_kernel<<<2048, 256, 0, stream>>>(part, q_b, Qbuf);
  qpack_kernel<<<dim3(2, LYR), 256, 0, stream>>>(Qbuf, cost, sint, qidx, Qblob);
  scores_kernel<<<dim3(32, 2, LYR), 512, 0, stream>>>(Qblob, Kblob, qidx, out);
  softmax_kernel<<<LYR * NH * NQ, 256, 0, stream>>>(out);
}

// Round 8
// 301.130 us; speedup vs baseline: 1.5092x; 1.5092x over previous
//
#include <hip/hip_runtime.h>
#include <hip/hip_bf16.h>
#include <math.h>

#define LYR 8
#define SEQ 4096
#define DIM 2048
#define NH 16
#define HD 128
#define NQ 32
#define NKV 256   // KVH*HD
#define NQE 2048  // H*HD

typedef __attribute__((ext_vector_type(8))) short short8;
typedef __attribute__((ext_vector_type(4))) float f32x4;

// workspace layout (float units)
#define WS_IRQ   0                        // 256
#define WS_ABLOB 256                      // 524288 floats = 1048576 shorts (A-frag blob for Q)
#define WS_COS   524544                   // 524288
#define WS_SIN   1048832                  // 524288
#define WS_QBUF  1573120                  // 524288  summed Q fp32 [l][q][2048]
#define WS_PART  2097408                  // 2097152 partials [ks4][l][q][2048]
#define WS_W2    4194560                  // 4194304 floats = 8388608 shorts (16MB)
#define WS_KBLOB 8388864                  // 8388608 floats = 16777216 shorts (32MB)
#define WS_QBLOB 16777472                 // 524288 floats = 1048576 shorts
// end 17301760 floats ~ 69.2 MB

__device__ __forceinline__ short f2bf(float x) {
  __hip_bfloat16 h = __float2bfloat16(x);
  return *(short*)&h;
}
__device__ __forceinline__ float bf2f(short s) {
  unsigned u = ((unsigned)(unsigned short)s) << 16;
  return __uint_as_float(u);
}

#define GLOAD16(srcp, dstp) \
  __builtin_amdgcn_global_load_lds( \
      (const __attribute__((address_space(1))) unsigned int*)(srcp), \
      (__attribute__((address_space(3))) unsigned int*)(dstp), 16, 0, 0)

// raw barrier: drain LDS ops only; leave global loads in flight across the barrier
#define RBAR() asm volatile("s_waitcnt lgkmcnt(0)\n\ts_barrier" ::: "memory")

// ---------------- prep: W' = ln_w*k_w -> frag-lane-linear bf16 hi/lo blob ----------------
__global__ __launch_bounds__(256) void prep_kernel(
    const float* __restrict__ ln_w, const float* __restrict__ k_w,
    short* __restrict__ W2) {
  int kb = blockIdx.x, l = blockIdx.y, t = threadIdx.x;
  const float* kwl = k_w + (size_t)l * DIM * NKV;
  const float* lnl = ln_w + l * DIM;
  short* blob = W2 + (size_t)(l * 64 + kb) * 16384;
  #pragma unroll
  for (int i = 0; i < 4; ++i) {
    int p = t + i * 256;
    int fi = p >> 6, lane = p & 63;
    int n = fi * 16 + (lane & 15);
    int k0 = kb * 32 + (lane >> 4) * 8;
    short hi8[8], lo8[8];
    #pragma unroll
    for (int e = 0; e < 8; ++e) {
      float v = lnl[k0 + e] * kwl[(size_t)(k0 + e) * NKV + n];
      short h = f2bf(v);
      hi8[e] = h;
      lo8[e] = f2bf(v - bf2f(h));
    }
    *(short8*)(blob + p * 8) = *(short8*)hi8;
    *(short8*)(blob + 8192 + p * 8) = *(short8*)lo8;
  }
}

// ---------------- rmsq: inv_rms for the 32 q rows ----------------
__global__ __launch_bounds__(256) void rmsq_kernel(const float* __restrict__ hs,
                                                   const int* __restrict__ q_idx,
                                                   float* __restrict__ irq) {
  int qi = blockIdx.x, l = blockIdx.y, t = threadIdx.x;
  int s = q_idx[qi];
  const float* row = hs + ((size_t)l * SEQ + s) * DIM;
  float4 v0 = *(const float4*)(row + t * 4);
  float4 v1 = *(const float4*)(row + t * 4 + 1024);
  float acc = v0.x*v0.x + v0.y*v0.y + v0.z*v0.z + v0.w*v0.w
            + v1.x*v1.x + v1.y*v1.y + v1.z*v1.z + v1.w*v1.w;
  #pragma unroll
  for (int off = 32; off >= 1; off >>= 1) acc += __shfl_down(acc, off);
  __shared__ float red[4];
  if ((t & 63) == 0) red[t >> 6] = acc;
  __syncthreads();
  if (t == 0) {
    float tot = red[0] + red[1] + red[2] + red[3];
    irq[l * NQ + qi] = rsqrtf(tot / (float)DIM + 1e-6f);
  }
}

// ---------------- cossin: mrope tables [S][HD] ----------------
__global__ void cossin_kernel(const int* __restrict__ pos_ids,
                              float* __restrict__ cost, float* __restrict__ sint) {
  int idx = blockIdx.x * 256 + threadIdx.x;
  int s = idx >> 7, d = idx & 127;
  int t = (d < 32) ? 0 : (d < 80 ? 1 : 2);
  int j = d & 63;
  double invf = pow(1000000.0, -(double)j / 64.0);
  double ph = (double)pos_ids[t * SEQ + s] * invf;
  cost[idx] = (float)cos(ph);
  sint[idx] = (float)sin(ph);
}

// ---------------- xqt: build A-frag blob for Q proj ----------------
__global__ __launch_bounds__(256) void xqt_kernel(
    const float* __restrict__ hs, const float* __restrict__ ln_w,
    const int* __restrict__ q_idx, const float* __restrict__ irq,
    short* __restrict__ Ablob) {
  __shared__ int qix[32];
  __shared__ float qir[32];
  int l = blockIdx.x, t = threadIdx.x;
  if (t < 32) { qix[t] = q_idx[t]; qir[t] = irq[l * NQ + t]; }
  __syncthreads();
  int lane = t & 63, g4 = t >> 6;
  short* base = Ablob + (size_t)l * 131072;
  int row = lane & 15, kgl = lane >> 4;
  for (int i = 0; i < 64; ++i) {
    int group = g4 * 64 + i;                 // (kb, half, mf)
    int kb = group >> 2, half = (group >> 1) & 1, mf = group & 1;
    int r = row + mf * 16;
    int k0 = kb * 32 + kgl * 8;
    const float* src = hs + ((size_t)l * SEQ + qix[r]) * DIM + k0;
    const float* lnp = ln_w + l * DIM + k0;
    float ir = qir[r];
    float4 v0 = *(const float4*)src;
    float4 v1 = *(const float4*)(src + 4);
    float4 w0 = *(const float4*)lnp;
    float4 w1 = *(const float4*)(lnp + 4);
    float av[8] = {v0.x*w0.x, v0.y*w0.y, v0.z*w0.z, v0.w*w0.w,
                   v1.x*w1.x, v1.y*w1.y, v1.z*w1.z, v1.w*w1.w};
    short o8[8];
    #pragma unroll
    for (int e = 0; e < 8; ++e) {
      float v = av[e] * ir;
      short h = f2bf(v);
      o8[e] = half ? f2bf(v - bf2f(h)) : h;
    }
    *(short8*)(base + group * 512 + lane * 8) = *(short8*)o8;
  }
}

// ---------------- kgemm: K proj bf16x3 MFMA, 4-step barrier groups + 8-slot A ring ----------------
// BM=64 BN=256 BK=32, 256 thr = 4 waves (1m x 4n). A: 8-slot LDS ring (64KB), write
// image for step n+4 at step n (data loaded at n-2); barrier only every 4 steps.
// B: direct global->VGPR frag loads, reg ping-pong, vmcnt-counted (never drained).
__global__ __launch_bounds__(256) void kgemm_kernel(
    const float* __restrict__ hs, const short* __restrict__ W2,
    const float* __restrict__ k_b, const float* __restrict__ cost,
    const float* __restrict__ sint, short* __restrict__ Kblob) {
  __shared__ __align__(1024) char SM[67584];
  // loop: ring of 8 step-images x 8KB (hi 4KB [mf*1KB], lo 4KB) = 64KB
  // epilogue: X[64][260] fp32 at [0,66560); irs at [66560,66816)

  int t = threadIdx.x;
  int fid = blockIdx.x;
  int l = fid & 7, sb = fid >> 3;
  int s0 = sb * 64;
  int lane = t & 63, w = t >> 6;
  int fr = lane & 15, kg = lane >> 4;
  int arow = t >> 2, akg = t & 3;

  const float* hrow = hs + ((size_t)l * SEQ + s0 + arow) * DIM + akg * 8;
  const char* wbase = (const char*)(W2 + (size_t)l * 64 * 16384);
  const char* wfrag = wbase + w * 1024 + lane * 16;   // B frags: nf stride 4096, half stride 16384, step stride 32768

  int awoff = (arow >> 4) * 1024 + (((akg * 16 + (arow & 15)) * 16) ^ (akg << 5));
  int aroff = (lane * 16) ^ ((lane >> 4) << 5);

  f32x4 acc[4][4];
  #pragma unroll
  for (int mf = 0; mf < 4; ++mf)
    #pragma unroll
    for (int nf = 0; nf < 4; ++nf) acc[mf][nf] = (f32x4){0.f, 0.f, 0.f, 0.f};
  float sq = 0.f;
  short8 B0h[4], B0l[4], B1h[4], B1l[4];
  float4 LA0, LA1, LB0, LB1;

  // ---- prologue: images 0..3, B(0) regs, prime LA=data4 LB=data5 ----
  #pragma unroll
  for (int s = 0; s < 4; ++s) {
    float4 a0 = *(const float4*)(hrow + s * 32);
    float4 a1 = *(const float4*)(hrow + s * 32 + 4);
    float av[8] = {a0.x, a0.y, a0.z, a0.w, a1.x, a1.y, a1.z, a1.w};
    short hi8[8], lo8[8];
    #pragma unroll
    for (int e = 0; e < 8; ++e) {
      sq += av[e] * av[e];
      short h = f2bf(av[e]);
      hi8[e] = h;
      lo8[e] = f2bf(av[e] - bf2f(h));
    }
    *(short8*)(SM + s * 8192 + awoff) = *(short8*)hi8;
    *(short8*)(SM + s * 8192 + 4096 + awoff) = *(short8*)lo8;
  }
  #pragma unroll
  for (int nf = 0; nf < 4; ++nf) {
    B0h[nf] = *(const short8*)(wfrag + nf * 4096);
    B0l[nf] = *(const short8*)(wfrag + nf * 4096 + 16384);
  }
  LA0 = *(const float4*)(hrow + 128); LA1 = *(const float4*)(hrow + 132);
  LB0 = *(const float4*)(hrow + 160); LB1 = *(const float4*)(hrow + 164);
  RBAR();

// GSTEP: one K-step at in-group position S.
// RD/WR: ring half bases; HA: hs group base; BF: W2 group base;
// UBH/UBL: B regs for this step; PBH/PBL: B regs to prefetch (step+1);
// L0/L1: A data regs consumed by W (data step n+4), reloaded if DOLD (data n+6).
#define GSTEP(S, RD, WR, HA, BF, UBH, UBL, PBH, PBL, L0, L1, DOLD, DOW, DOPB) do { \
    if (DOPB) { \
      const char* bsrc_ = (BF) + (size_t)((S) + 1) * 32768; \
      _Pragma("unroll") \
      for (int nf = 0; nf < 4; ++nf) { \
        PBH[nf] = *(const short8*)(bsrc_ + nf * 4096); \
        PBL[nf] = *(const short8*)(bsrc_ + nf * 4096 + 16384); \
      } \
    } \
    float4 na0_, na1_; \
    if (DOLD) { \
      na0_ = *(const float4*)((HA) + ((S) + 6) * 32); \
      na1_ = *(const float4*)((HA) + ((S) + 6) * 32 + 4); \
    } \
    short8 ah_[4], al_[4]; \
    _Pragma("unroll") \
    for (int mf = 0; mf < 4; ++mf) { \
      ah_[mf] = *(const short8*)((RD) + (S) * 8192 + mf * 1024 + aroff); \
      al_[mf] = *(const short8*)((RD) + (S) * 8192 + 4096 + mf * 1024 + aroff); \
    } \
    _Pragma("unroll") \
    for (int nf = 0; nf < 4; ++nf) { \
      _Pragma("unroll") \
      for (int mf = 0; mf < 4; ++mf) { \
        acc[mf][nf] = __builtin_amdgcn_mfma_f32_16x16x32_bf16(ah_[mf], UBH[nf], acc[mf][nf], 0, 0, 0); \
        acc[mf][nf] = __builtin_amdgcn_mfma_f32_16x16x32_bf16(ah_[mf], UBL[nf], acc[mf][nf], 0, 0, 0); \
        acc[mf][nf] = __builtin_amdgcn_mfma_f32_16x16x32_bf16(al_[mf], UBH[nf], acc[mf][nf], 0, 0, 0); \
      } \
    } \
    if (DOW) { \
      float av_[8] = {L0.x, L0.y, L0.z, L0.w, L1.x, L1.y, L1.z, L1.w}; \
      short hi8_[8], lo8_[8]; \
      _Pragma("unroll") \
      for (int e = 0; e < 8; ++e) { \
        sq += av_[e] * av_[e]; \
        short h_ = f2bf(av_[e]); \
        hi8_[e] = h_; \
        lo8_[e] = f2bf(av_[e] - bf2f(h_)); \
      } \
      *(short8*)((WR) + (S) * 8192 + awoff) = *(short8*)hi8_; \
      *(short8*)((WR) + (S) * 8192 + 4096 + awoff) = *(short8*)lo8_; \
    } \
    if (DOLD) { L0 = na0_; L1 = na1_; } \
  } while (0)

  // groups 0..13 (steps 0..55), paired even/odd
  for (int kb2 = 0; kb2 < 7; ++kb2) {
    const float* hA = hrow + kb2 * 256;
    const char* bfA = wfrag + (size_t)kb2 * 262144;
    GSTEP(0, SM, SM + 32768, hA, bfA, B0h, B0l, B1h, B1l, LA0, LA1, 1, 1, 1);
    GSTEP(1, SM, SM + 32768, hA, bfA, B1h, B1l, B0h, B0l, LB0, LB1, 1, 1, 1);
    GSTEP(2, SM, SM + 32768, hA, bfA, B0h, B0l, B1h, B1l, LA0, LA1, 1, 1, 1);
    GSTEP(3, SM, SM + 32768, hA, bfA, B1h, B1l, B0h, B0l, LB0, LB1, 1, 1, 1);
    RBAR();
    const float* hB = hA + 128;
    const char* bfB = bfA + 131072;
    GSTEP(0, SM + 32768, SM, hB, bfB, B0h, B0l, B1h, B1l, LA0, LA1, 1, 1, 1);
    GSTEP(1, SM + 32768, SM, hB, bfB, B1h, B1l, B0h, B0l, LB0, LB1, 1, 1, 1);
    GSTEP(2, SM + 32768, SM, hB, bfB, B0h, B0l, B1h, B1l, LA0, LA1, 1, 1, 1);
    GSTEP(3, SM + 32768, SM, hB, bfB, B1h, B1l, B0h, B0l, LB0, LB1, 1, 1, 1);
    RBAR();
  }
  // group 14 (steps 56..59): stop loads after data 63
  {
    const float* hA = hrow + 1792;
    const char* bf = wfrag + (size_t)14 * 131072;
    GSTEP(0, SM, SM + 32768, hA, bf, B0h, B0l, B1h, B1l, LA0, LA1, 1, 1, 1);
    GSTEP(1, SM, SM + 32768, hA, bf, B1h, B1l, B0h, B0l, LB0, LB1, 1, 1, 1);
    GSTEP(2, SM, SM + 32768, hA, bf, B0h, B0l, B1h, B1l, LA0, LA1, 0, 1, 1);
    GSTEP(3, SM, SM + 32768, hA, bf, B1h, B1l, B0h, B0l, LB0, LB1, 0, 1, 1);
    RBAR();
  }
  // group 15 (steps 60..63): pure compute
  {
    const char* bf = wfrag + (size_t)15 * 131072;
    GSTEP(0, SM + 32768, SM, hrow, bf, B0h, B0l, B1h, B1l, LA0, LA1, 0, 0, 1);
    GSTEP(1, SM + 32768, SM, hrow, bf, B1h, B1l, B0h, B0l, LB0, LB1, 0, 0, 1);
    GSTEP(2, SM + 32768, SM, hrow, bf, B0h, B0l, B1h, B1l, LA0, LA1, 0, 0, 1);
    GSTEP(3, SM + 32768, SM, hrow, bf, B1h, B1l, B0h, B0l, LB0, LB1, 0, 0, 0);
  }
#undef GSTEP

  // ---- epilogue ----
  sq += __shfl_xor(sq, 1);
  sq += __shfl_xor(sq, 2);
  float* irs = (float*)(SM + 66560);
  if ((t & 3) == 0) irs[arow] = rsqrtf(sq / (float)DIM + 1e-6f);
  __syncthreads();

  float* Kraw = (float*)SM;
  int j = w * 16 + fr;
  float bias0 = k_b[l * NKV + j];
  float bias1 = k_b[l * NKV + j + 64];
  float bias2 = k_b[l * NKV + j + 128];
  float bias3 = k_b[l * NKV + j + 192];
  #pragma unroll
  for (int mf = 0; mf < 4; ++mf) {
    #pragma unroll
    for (int r = 0; r < 4; ++r) {
      int row = mf * 16 + kg * 4 + r;
      int s = s0 + row;
      float ir = irs[row];
      float v0 = acc[mf][0][r] * ir + bias0;
      float v1 = acc[mf][1][r] * ir + bias1;
      float v2 = acc[mf][2][r] * ir + bias2;
      float v3 = acc[mf][3][r] * ir + bias3;
      float cj = cost[s * HD + j], sj = sint[s * HD + j];
      float cj2 = cost[s * HD + j + 64], sj2 = sint[s * HD + j + 64];
      float* kr = Kraw + row * 260;
      kr[j]       = v0 * cj - v1 * sj;
      kr[j + 64]  = v1 * cj2 + v0 * sj2;
      kr[j + 128] = v2 * cj - v3 * sj;
      kr[j + 192] = v3 * cj2 + v2 * sj2;
    }
  }
  __syncthreads();

  int kc = sb >> 1, fb = (sb & 1) * 4;
  #pragma unroll
  for (int i = 0; i < 8; ++i) {
    int c = t + i * 256;
    int lc = c & 63, fl = (c >> 6) & 3, ts = (c >> 8) & 3, kv = c >> 10;
    int key = fl * 16 + (lc & 15);
    int d0 = kv * 128 + ts * 32 + (lc >> 4) * 8;
    float4 x0 = *(const float4*)(Kraw + key * 260 + d0);
    float4 x1 = *(const float4*)(Kraw + key * 260 + d0 + 4);
    float av[8] = {x0.x, x0.y, x0.z, x0.w, x1.x, x1.y, x1.z, x1.w};
    short hi8[8], lo8[8];
    #pragma unroll
    for (int e = 0; e < 8; ++e) {
      short h = f2bf(av[e]);
      hi8[e] = h;
      lo8[e] = f2bf(av[e] - bf2f(h));
    }
    short* bb = Kblob + (size_t)((l * 2 + kv) * 32 + kc) * 32768
              + (size_t)((ts * 2 + 0) * 8 + fb + fl) * 512 + lc * 8;
    *(short8*)bb = *(short8*)hi8;
    *(short8*)(bb + 4096) = *(short8*)lo8;
  }
}

// ---------------- qgemm: Q = xq . q_w via bf16x3 MFMA, q_w streamed fp32 ----------------
__global__ __launch_bounds__(512) void qgemm_kernel(
    const float* __restrict__ q_w, const short* __restrict__ Ablob,
    float* __restrict__ part) {
  __shared__ __align__(1024) char SM[131072];
  int t = threadIdx.x;
  int nc = blockIdx.x, ks = blockIdx.y, l = blockIdx.z;
  int lane = t & 63, w = t >> 6;
  int fr = lane & 15, kg = lane >> 4;
  const char* abase = (const char*)(Ablob + (size_t)l * 131072 + (size_t)ks * 32768);
  const float* qwl = q_w + (size_t)l * DIM * NQE;

  #pragma unroll
  for (int c = 0; c < 8; ++c) {
    int chunk = w * 8 + c;
    GLOAD16(abase + chunk * 1024 + lane * 16, SM + chunk * 1024);
  }
  #pragma unroll
  for (int c = 0; c < 4; ++c) {
    int r = w * 4 + c;
    GLOAD16((const char*)(qwl + (size_t)(ks * 512 + r) * NQE + nc * 256) + lane * 16,
            SM + 65536 + r * 1024 + lane * 16);
  }
  f32x4 acc[2][2];
  #pragma unroll
  for (int mf = 0; mf < 2; ++mf)
    #pragma unroll
    for (int nf = 0; nf < 2; ++nf) acc[mf][nf] = (f32x4){0.f, 0.f, 0.f, 0.f};
  __syncthreads();

  for (int ts = 0; ts < 16; ++ts) {
    int buf = ts & 1;
    if (ts < 15) {
      #pragma unroll
      for (int c = 0; c < 4; ++c) {
        int r = w * 4 + c;
        GLOAD16((const char*)(qwl + (size_t)(ks * 512 + (ts + 1) * 32 + r) * NQE + nc * 256) + lane * 16,
                SM + 65536 + (buf ^ 1) * 32768 + r * 1024 + lane * 16);
      }
    }
    short8 ah[2], al[2];
    #pragma unroll
    for (int mf = 0; mf < 2; ++mf) {
      ah[mf] = *(const short8*)(SM + ts * 4096 + mf * 1024 + lane * 16);
      al[mf] = *(const short8*)(SM + ts * 4096 + 2048 + mf * 1024 + lane * 16);
    }
    const float* bt = (const float*)(SM + 65536 + buf * 32768);
    #pragma unroll
    for (int nf = 0; nf < 2; ++nf) {
      int c = w * 32 + nf * 16 + fr;
      short bh8[8], bl8[8];
      #pragma unroll
      for (int e = 0; e < 8; ++e) {
        float v = bt[(kg * 8 + e) * 256 + c];
        short h = f2bf(v);
        bh8[e] = h;
        bl8[e] = f2bf(v - bf2f(h));
      }
      short8 bh = *(short8*)bh8, bl = *(short8*)bl8;
      #pragma unroll
      for (int mf = 0; mf < 2; ++mf) {
        acc[mf][nf] = __builtin_amdgcn_mfma_f32_16x16x32_bf16(ah[mf], bh, acc[mf][nf], 0, 0, 0);
        acc[mf][nf] = __builtin_amdgcn_mfma_f32_16x16x32_bf16(ah[mf], bl, acc[mf][nf], 0, 0, 0);
        acc[mf][nf] = __builtin_amdgcn_mfma_f32_16x16x32_bf16(al[mf], bh, acc[mf][nf], 0, 0, 0);
      }
    }
    __syncthreads();
  }

  #pragma unroll
  for (int mf = 0; mf < 2; ++mf) {
    #pragma unroll
    for (int r = 0; r < 4; ++r) {
      int row = mf * 16 + kg * 4 + r;
      float* prow = part + ((size_t)((ks * LYR + l) * NQ + row)) * NQE + nc * 256;
      #pragma unroll
      for (int nf = 0; nf < 2; ++nf) {
        int col = w * 32 + nf * 16 + fr;
        prow[col] = acc[mf][nf][r];
      }
    }
  }
}

// ---------------- qred: sum 4 k-split partials + bias -> Qbuf ----------------
__global__ __launch_bounds__(256) void qred_kernel(
    const float* __restrict__ part, const float* __restrict__ q_b,
    float* __restrict__ Qbuf) {
  int idx = blockIdx.x * 256 + threadIdx.x;
  int n = idx & 2047, q = (idx >> 11) & 31, l = idx >> 16;
  float v = q_b[l * NQE + n];
  #pragma unroll
  for (int ks = 0; ks < 4; ++ks)
    v += part[((size_t)((ks * LYR + l) * NQ + q)) * NQE + n];
  Qbuf[((size_t)l * NQ + q) * NQE + n] = v;
}

// ---------------- qpack: rope Q + split to frag-lane-linear blob ----------------
__global__ __launch_bounds__(256) void qpack_kernel(
    const float* __restrict__ Qbuf, const float* __restrict__ cost,
    const float* __restrict__ sint, const int* __restrict__ q_idx,
    short* __restrict__ Qblob) {
  int kv = blockIdx.x, l = blockIdx.y, t = threadIdx.x;
  short* blob = Qblob + (size_t)(l * 2 + kv) * 65536;
  #pragma unroll
  for (int i = 0; i < 16; ++i) {
    int p = t + i * 256;
    int ts = p >> 10, f = (p >> 6) & 15, lane = p & 63;
    int row = f * 16 + (lane & 15);
    int hh = row >> 5, q = row & 31;
    int h = kv * 8 + hh;
    int d0 = ts * 32 + (lane >> 4) * 8;
    int s = q_idx[q];
    const float* qrow = Qbuf + ((size_t)l * NQ + q) * NQE + h * HD;
    const float* ct = cost + s * HD;
    const float* st = sint + s * HD;
    short hi8[8], lo8[8];
    #pragma unroll
    for (int e = 0; e < 8; ++e) {
      int d = d0 + e;
      float x = qrow[d];
      float xp = qrow[d ^ 64];
      float v = (d < 64) ? (x * ct[d] - xp * st[d]) : (x * ct[d] + xp * st[d]);
      short h2 = f2bf(v);
      hi8[e] = h2;
      lo8[e] = f2bf(v - bf2f(h2));
    }
    *(short8*)(blob + ((ts * 2 + 0) * 16 + f) * 512 + lane * 8) = *(short8*)hi8;
    *(short8*)(blob + ((ts * 2 + 1) * 16 + f) * 512 + lane * 8) = *(short8*)lo8;
  }
}

// ---------------- scores: bf16x3 MFMA, M=256 (8 heads x 32 q) x 128 keys ----------------
__global__ __launch_bounds__(512) void scores_kernel(
    const short* __restrict__ Qblob, const short* __restrict__ Kblob,
    const int* __restrict__ q_idx, float* __restrict__ out) {
  __shared__ short Qs[2][16384];
  __shared__ short Ks[2][8192];
  __shared__ int qiv[32];
  int t = threadIdx.x;
  int kc = blockIdx.x, kv = blockIdx.y, l = blockIdx.z;
  int lane = t & 63, w = t >> 6;
  int wm = w >> 1, wn = w & 1;
  if (t < 32) qiv[t] = q_idx[t];
  const char* qsrc = (const char*)(Qblob + (size_t)(l * 2 + kv) * 65536);
  const char* ksrc = (const char*)(Kblob + (size_t)((l * 2 + kv) * 32 + kc) * 32768);
  #pragma unroll
  for (int c = 0; c < 4; ++c) {
    int off = (w * 4 + c) * 1024;
    GLOAD16(qsrc + off + lane * 16, (char*)Qs[0] + off);
  }
  #pragma unroll
  for (int c = 0; c < 2; ++c) {
    int off = (w * 2 + c) * 1024;
    GLOAD16(ksrc + off + lane * 16, (char*)Ks[0] + off);
  }
  f32x4 acc[4][4];
  #pragma unroll
  for (int mf = 0; mf < 4; ++mf)
    #pragma unroll
    for (int nf = 0; nf < 4; ++nf) acc[mf][nf] = (f32x4){0.f, 0.f, 0.f, 0.f};
  __syncthreads();
  for (int ts = 0; ts < 4; ++ts) {
    int buf = ts & 1;
    if (ts < 3) {
      const char* qs = qsrc + (ts + 1) * 32768;
      const char* ks = ksrc + (ts + 1) * 16384;
      #pragma unroll
      for (int c = 0; c < 4; ++c) {
        int off = (w * 4 + c) * 1024;
        GLOAD16(qs + off + lane * 16, (char*)Qs[(ts + 1) & 1] + off);
      }
      #pragma unroll
      for (int c = 0; c < 2; ++c) {
        int off = (w * 2 + c) * 1024;
        GLOAD16(ks + off + lane * 16, (char*)Ks[(ts + 1) & 1] + off);
      }
    }
    short8 ah[4], al[4];
    #pragma unroll
    for (int mf = 0; mf < 4; ++mf) {
      int f = wm * 4 + mf;
      ah[mf] = *(const short8*)(Qs[buf] + f * 512 + lane * 8);
      al[mf] = *(const short8*)(Qs[buf] + 8192 + f * 512 + lane * 8);
    }
    #pragma unroll
    for (int nf = 0; nf < 4; ++nf) {
      int f = wn * 4 + nf;
      short8 bh = *(const short8*)(Ks[buf] + f * 512 + lane * 8);
      short8 bl = *(const short8*)(Ks[buf] + 4096 + f * 512 + lane * 8);
      #pragma unroll
      for (int mf = 0; mf < 4; ++mf) {
        acc[mf][nf] = __builtin_amdgcn_mfma_f32_16x16x32_bf16(ah[mf], bh, acc[mf][nf], 0, 0, 0);
        acc[mf][nf] = __builtin_amdgcn_mfma_f32_16x16x32_bf16(ah[mf], bl, acc[mf][nf], 0, 0, 0);
        acc[mf][nf] = __builtin_amdgcn_mfma_f32_16x16x32_bf16(al[mf], bh, acc[mf][nf], 0, 0, 0);
      }
    }
    __syncthreads();
  }
  const float scale = 0.088388347648318447f;
  #pragma unroll
  for (int mf = 0; mf < 4; ++mf) {
    #pragma unroll
    for (int r = 0; r < 4; ++r) {
      int rr = wm * 64 + mf * 16 + (lane >> 4) * 4 + r;
      int hh = rr >> 5, q = rr & 31;
      int qv = qiv[q];
      float* orow = out + (((size_t)(l * NH + kv * 8 + hh)) * NQ + q) * SEQ;
      #pragma unroll
      for (int nf = 0; nf < 4; ++nf) {
        int key = kc * 128 + (wn * 4 + nf) * 16 + (lane & 15);
        orow[key] = (key > qv) ? -1e9f : acc[mf][nf][r] * scale;
      }
    }
  }
}

// ---------------- softmax over S ----------------
__global__ __launch_bounds__(256) void softmax_kernel(float* __restrict__ out) {
  size_t row = blockIdx.x;
  float* p = out + row * SEQ;
  int t = threadIdx.x;
  float4 v[4];
  float mx = -1e30f;
  #pragma unroll
  for (int i = 0; i < 4; ++i) {
    v[i] = *(const float4*)(p + t * 4 + i * 1024);
    mx = fmaxf(mx, fmaxf(fmaxf(v[i].x, v[i].y), fmaxf(v[i].z, v[i].w)));
  }
  #pragma unroll
  for (int off = 32; off >= 1; off >>= 1) mx = fmaxf(mx, __shfl_xor(mx, off));
  __shared__ float red[4];
  if ((t & 63) == 0) red[t >> 6] = mx;
  __syncthreads();
  mx = fmaxf(fmaxf(red[0], red[1]), fmaxf(red[2], red[3]));
  __syncthreads();
  float sum = 0.f;
  #pragma unroll
  for (int i = 0; i < 4; ++i) {
    v[i].x = __expf(v[i].x - mx); v[i].y = __expf(v[i].y - mx);
    v[i].z = __expf(v[i].z - mx); v[i].w = __expf(v[i].w - mx);
    sum += v[i].x + v[i].y + v[i].z + v[i].w;
  }
  #pragma unroll
  for (int off = 32; off >= 1; off >>= 1) sum += __shfl_xor(sum, off);
  if ((t & 63) == 0) red[t >> 6] = sum;
  __syncthreads();
  sum = red[0] + red[1] + red[2] + red[3];
  float inv = 1.f / sum;
  #pragma unroll
  for (int i = 0; i < 4; ++i) {
    v[i].x *= inv; v[i].y *= inv; v[i].z *= inv; v[i].w *= inv;
    *(float4*)(p + t * 4 + i * 1024) = v[i];
  }
}

extern "C" void kernel_launch(void* const* d_in, const int* in_sizes, int n_in,
                              void* d_out, int out_size, void* d_ws, size_t ws_size,
                              hipStream_t stream) {
  const float* hs   = (const float*)d_in[0];
  const float* ln_w = (const float*)d_in[1];
  const float* q_w  = (const float*)d_in[2];
  const float* q_b  = (const float*)d_in[3];
  const float* k_w  = (const float*)d_in[4];
  const float* k_b  = (const float*)d_in[5];
  const int* pos    = (const int*)d_in[6];
  const int* qidx   = (const int*)d_in[7];
  float* out = (float*)d_out;
  float* ws = (float*)d_ws;
  float* irq   = ws + WS_IRQ;
  short* Ablob = (short*)(ws + WS_ABLOB);
  float* cost  = ws + WS_COS;
  float* sint  = ws + WS_SIN;
  float* Qbuf  = ws + WS_QBUF;
  float* part  = ws + WS_PART;
  short* W2    = (short*)(ws + WS_W2);
  short* Kblob = (short*)(ws + WS_KBLOB);
  short* Qblob = (short*)(ws + WS_QBLOB);

  prep_kernel<<<dim3(64, LYR), 256, 0, stream>>>(ln_w, k_w, W2);
  rmsq_kernel<<<dim3(NQ, LYR), 256, 0, stream>>>(hs, qidx, irq);
  cossin_kernel<<<(SEQ * HD) / 256, 256, 0, stream>>>(pos, cost, sint);
  xqt_kernel<<<LYR, 256, 0, stream>>>(hs, ln_w, qidx, irq, Ablob);
  kgemm_kernel<<<512, 256, 0, stream>>>(hs, W2, k_b, cost, sint, Kblob);
  qgemm_kernel<<<dim3(8, 4, LYR), 512, 0, stream>>>(q_w, Ablob, part);
  qred_kernel<<<2048, 256, 0, stream>>>(part, q_b, Qbuf);
  qpack_kernel<<<dim3(2, LYR), 256, 0, stream>>>(Qbuf, cost, sint, qidx, Qblob);
  scores_kernel<<<dim3(32, 2, LYR), 512, 0, stream>>>(Qblob, Kblob, qidx, out);
  softmax_kernel<<<LYR * NH * NQ, 256, 0, stream>>>(out);
}

// Round 9
// 286.235 us; speedup vs baseline: 1.5877x; 1.0520x over previous
//
#include <hip/hip_runtime.h>
#include <hip/hip_bf16.h>
#include <math.h>

#define LYR 8
#define SEQ 4096
#define DIM 2048
#define NH 16
#define HD 128
#define NQ 32
#define NKV 256   // KVH*HD
#define NQE 2048  // H*HD

typedef __attribute__((ext_vector_type(8))) short short8;
typedef __attribute__((ext_vector_type(4))) float f32x4;

// workspace layout (float units)
#define WS_IRQ   0                        // 256
#define WS_ABLOB 256                      // 524288 floats = 1048576 shorts (A-frag blob for Q)
#define WS_COS   524544                   // 524288
#define WS_SIN   1048832                  // 524288
#define WS_QBUF  1573120                  // 524288  summed Q fp32 [l][q][2048]
#define WS_PART  2097408                  // 2097152 partials [ks4][l][q][2048]
#define WS_W2    4194560                  // 4194304 floats = 8388608 shorts (16MB)
#define WS_KBLOB 8388864                  // 8388608 floats = 16777216 shorts (32MB)
#define WS_QBLOB 16777472                 // 524288 floats = 1048576 shorts
// end 17301760 floats ~ 69.2 MB

__device__ __forceinline__ short f2bf(float x) {
  __hip_bfloat16 h = __float2bfloat16(x);
  return *(short*)&h;
}
__device__ __forceinline__ float bf2f(short s) {
  unsigned u = ((unsigned)(unsigned short)s) << 16;
  return __uint_as_float(u);
}

#define GLOAD16(srcp, dstp) \
  __builtin_amdgcn_global_load_lds( \
      (const __attribute__((address_space(1))) unsigned int*)(srcp), \
      (__attribute__((address_space(3))) unsigned int*)(dstp), 16, 0, 0)

// raw barrier: drain LDS ops only; leave global loads in flight across the barrier
#define RBAR() asm volatile("s_waitcnt lgkmcnt(0)\n\ts_barrier" ::: "memory")

// ---------------- prep: W' = ln_w*k_w -> frag-lane-linear bf16 hi/lo blob ----------------
__global__ __launch_bounds__(256) void prep_kernel(
    const float* __restrict__ ln_w, const float* __restrict__ k_w,
    short* __restrict__ W2) {
  int kb = blockIdx.x, l = blockIdx.y, t = threadIdx.x;
  const float* kwl = k_w + (size_t)l * DIM * NKV;
  const float* lnl = ln_w + l * DIM;
  short* blob = W2 + (size_t)(l * 64 + kb) * 16384;
  #pragma unroll
  for (int i = 0; i < 4; ++i) {
    int p = t + i * 256;
    int fi = p >> 6, lane = p & 63;
    int n = fi * 16 + (lane & 15);
    int k0 = kb * 32 + (lane >> 4) * 8;
    short hi8[8], lo8[8];
    #pragma unroll
    for (int e = 0; e < 8; ++e) {
      float v = lnl[k0 + e] * kwl[(size_t)(k0 + e) * NKV + n];
      short h = f2bf(v);
      hi8[e] = h;
      lo8[e] = f2bf(v - bf2f(h));
    }
    *(short8*)(blob + p * 8) = *(short8*)hi8;
    *(short8*)(blob + 8192 + p * 8) = *(short8*)lo8;
  }
}

// ---------------- rmsq: inv_rms for the 32 q rows ----------------
__global__ __launch_bounds__(256) void rmsq_kernel(const float* __restrict__ hs,
                                                   const int* __restrict__ q_idx,
                                                   float* __restrict__ irq) {
  int qi = blockIdx.x, l = blockIdx.y, t = threadIdx.x;
  int s = q_idx[qi];
  const float* row = hs + ((size_t)l * SEQ + s) * DIM;
  float4 v0 = *(const float4*)(row + t * 4);
  float4 v1 = *(const float4*)(row + t * 4 + 1024);
  float acc = v0.x*v0.x + v0.y*v0.y + v0.z*v0.z + v0.w*v0.w
            + v1.x*v1.x + v1.y*v1.y + v1.z*v1.z + v1.w*v1.w;
  #pragma unroll
  for (int off = 32; off >= 1; off >>= 1) acc += __shfl_down(acc, off);
  __shared__ float red[4];
  if ((t & 63) == 0) red[t >> 6] = acc;
  __syncthreads();
  if (t == 0) {
    float tot = red[0] + red[1] + red[2] + red[3];
    irq[l * NQ + qi] = rsqrtf(tot / (float)DIM + 1e-6f);
  }
}

// ---------------- cossin: mrope tables [S][HD] ----------------
__global__ void cossin_kernel(const int* __restrict__ pos_ids,
                              float* __restrict__ cost, float* __restrict__ sint) {
  int idx = blockIdx.x * 256 + threadIdx.x;
  int s = idx >> 7, d = idx & 127;
  int t = (d < 32) ? 0 : (d < 80 ? 1 : 2);
  int j = d & 63;
  double invf = pow(1000000.0, -(double)j / 64.0);
  double ph = (double)pos_ids[t * SEQ + s] * invf;
  cost[idx] = (float)cos(ph);
  sint[idx] = (float)sin(ph);
}

// ---------------- xqt: build A-frag blob for Q proj ----------------
__global__ __launch_bounds__(256) void xqt_kernel(
    const float* __restrict__ hs, const float* __restrict__ ln_w,
    const int* __restrict__ q_idx, const float* __restrict__ irq,
    short* __restrict__ Ablob) {
  __shared__ int qix[32];
  __shared__ float qir[32];
  int l = blockIdx.x, t = threadIdx.x;
  if (t < 32) { qix[t] = q_idx[t]; qir[t] = irq[l * NQ + t]; }
  __syncthreads();
  int lane = t & 63, g4 = t >> 6;
  short* base = Ablob + (size_t)l * 131072;
  int row = lane & 15, kgl = lane >> 4;
  for (int i = 0; i < 64; ++i) {
    int group = g4 * 64 + i;                 // (kb, half, mf)
    int kb = group >> 2, half = (group >> 1) & 1, mf = group & 1;
    int r = row + mf * 16;
    int k0 = kb * 32 + kgl * 8;
    const float* src = hs + ((size_t)l * SEQ + qix[r]) * DIM + k0;
    const float* lnp = ln_w + l * DIM + k0;
    float ir = qir[r];
    float4 v0 = *(const float4*)src;
    float4 v1 = *(const float4*)(src + 4);
    float4 w0 = *(const float4*)lnp;
    float4 w1 = *(const float4*)(lnp + 4);
    float av[8] = {v0.x*w0.x, v0.y*w0.y, v0.z*w0.z, v0.w*w0.w,
                   v1.x*w1.x, v1.y*w1.y, v1.z*w1.z, v1.w*w1.w};
    short o8[8];
    #pragma unroll
    for (int e = 0; e < 8; ++e) {
      float v = av[e] * ir;
      short h = f2bf(v);
      o8[e] = half ? f2bf(v - bf2f(h)) : h;
    }
    *(short8*)(base + group * 512 + lane * 8) = *(short8*)o8;
  }
}

// ---------------- kgemm: K proj bf16x3 MFMA, BN=128 (one kv head), 4 blocks/CU ----------------
// BM=64 BN=128 BK=32, 256 thr = 4 waves (1m x 4n over 128 cols, 2 nf frags each).
// Grid 1024 = 4 independent blocks/CU: barrier stalls of one block hide under
// the other 3 blocks' MFMA (TLP). A: LDS dbuf 16KB; B: reg ping-pong from W2.
__global__ __launch_bounds__(256, 4) void kgemm_kernel(
    const float* __restrict__ hs, const short* __restrict__ W2,
    const float* __restrict__ k_b, const float* __restrict__ cost,
    const float* __restrict__ sint, short* __restrict__ Kblob) {
  __shared__ __align__(1024) char SM[34816];
  // loop: A dbuf 2 x 8KB at [0,16384)
  // epilogue: Kraw[64][132] fp32 at [0,33792); irs at [33792,34048)

  int t = threadIdx.x;
  int fid = blockIdx.x;
  int l = fid & 7, nh = (fid >> 3) & 1, sb = fid >> 4;
  int s0 = sb * 64;
  int lane = t & 63, w = t >> 6;
  int fr = lane & 15, kg = lane >> 4;
  int arow = t >> 2, akg = t & 3;

  const float* hrow = hs + ((size_t)l * SEQ + s0 + arow) * DIM + akg * 8;
  const char* wbase = (const char*)(W2 + (size_t)l * 64 * 16384);
  const char* wfrag = wbase + (nh * 8 + w) * 1024 + lane * 16;  // nf stride 4096B, lo +16384B, kb stride 32768B

  int awoff = (arow >> 4) * 1024 + (((akg * 16 + (arow & 15)) * 16) ^ (akg << 5));
  int aroff = (lane * 16) ^ ((lane >> 4) << 5);

  f32x4 acc[4][2];
  #pragma unroll
  for (int mf = 0; mf < 4; ++mf)
    #pragma unroll
    for (int nf = 0; nf < 2; ++nf) acc[mf][nf] = (f32x4){0.f, 0.f, 0.f, 0.f};
  float sq = 0.f;
  short8 B0h[2], B0l[2], B1h[2], B1l[2];

  // prologue: B(0) -> B0 regs; A(0) load+cvt+write buf0
  {
    B0h[0] = *(const short8*)(wfrag);
    B0l[0] = *(const short8*)(wfrag + 16384);
    B0h[1] = *(const short8*)(wfrag + 4096);
    B0l[1] = *(const short8*)(wfrag + 4096 + 16384);
    float4 a0 = *(const float4*)(hrow);
    float4 a1 = *(const float4*)(hrow + 4);
    float av[8] = {a0.x, a0.y, a0.z, a0.w, a1.x, a1.y, a1.z, a1.w};
    short hi8[8], lo8[8];
    #pragma unroll
    for (int e = 0; e < 8; ++e) {
      sq += av[e] * av[e];
      short h = f2bf(av[e]);
      hi8[e] = h;
      lo8[e] = f2bf(av[e] - bf2f(h));
    }
    *(short8*)(SM + awoff) = *(short8*)hi8;
    *(short8*)(SM + 4096 + awoff) = *(short8*)lo8;
  }
  RBAR();

#define KSTEP(KB, UBH, UBL, PBH, PBL) do { \
    int buf_ = (KB) & 1; \
    const char* asb_ = SM + buf_ * 8192; \
    float4 a0_, a1_; \
    if ((KB) < 63) { \
      const char* bsrc_ = wfrag + (size_t)((KB) + 1) * 32768; \
      PBH[0] = *(const short8*)(bsrc_); \
      PBL[0] = *(const short8*)(bsrc_ + 16384); \
      PBH[1] = *(const short8*)(bsrc_ + 4096); \
      PBL[1] = *(const short8*)(bsrc_ + 4096 + 16384); \
      a0_ = *(const float4*)(hrow + ((KB) + 1) * 32); \
      a1_ = *(const float4*)(hrow + ((KB) + 1) * 32 + 4); \
    } \
    short8 ah_[4], al_[4]; \
    _Pragma("unroll") \
    for (int mf = 0; mf < 4; ++mf) { \
      ah_[mf] = *(const short8*)(asb_ + mf * 1024 + aroff); \
      al_[mf] = *(const short8*)(asb_ + 4096 + mf * 1024 + aroff); \
    } \
    _Pragma("unroll") \
    for (int nf = 0; nf < 2; ++nf) { \
      _Pragma("unroll") \
      for (int mf = 0; mf < 4; ++mf) { \
        acc[mf][nf] = __builtin_amdgcn_mfma_f32_16x16x32_bf16(ah_[mf], UBH[nf], acc[mf][nf], 0, 0, 0); \
        acc[mf][nf] = __builtin_amdgcn_mfma_f32_16x16x32_bf16(ah_[mf], UBL[nf], acc[mf][nf], 0, 0, 0); \
        acc[mf][nf] = __builtin_amdgcn_mfma_f32_16x16x32_bf16(al_[mf], UBH[nf], acc[mf][nf], 0, 0, 0); \
      } \
    } \
    if ((KB) < 63) { \
      char* asn_ = SM + (buf_ ^ 1) * 8192; \
      float av_[8] = {a0_.x, a0_.y, a0_.z, a0_.w, a1_.x, a1_.y, a1_.z, a1_.w}; \
      short hi8_[8], lo8_[8]; \
      _Pragma("unroll") \
      for (int e = 0; e < 8; ++e) { \
        sq += av_[e] * av_[e]; \
        short h_ = f2bf(av_[e]); \
        hi8_[e] = h_; \
        lo8_[e] = f2bf(av_[e] - bf2f(h_)); \
      } \
      *(short8*)(asn_ + awoff) = *(short8*)hi8_; \
      *(short8*)(asn_ + 4096 + awoff) = *(short8*)lo8_; \
    } \
    RBAR(); \
  } while (0)

  for (int kb2 = 0; kb2 < 32; ++kb2) {
    KSTEP(2 * kb2,     B0h, B0l, B1h, B1l);
    KSTEP(2 * kb2 + 1, B1h, B1l, B0h, B0l);
  }
#undef KSTEP

  // ---- epilogue ----
  sq += __shfl_xor(sq, 1);
  sq += __shfl_xor(sq, 2);
  float* irs = (float*)(SM + 33792);
  if ((t & 3) == 0) irs[arow] = rsqrtf(sq / (float)DIM + 1e-6f);
  __syncthreads();

  // ir*acc + bias + rope -> Kraw[64][132] (head-local dims 0..127)
  float* Kraw = (float*)SM;
  int j = w * 16 + fr;                       // 0..63 within head
  float bias0 = k_b[l * NKV + nh * 128 + j];
  float bias1 = k_b[l * NKV + nh * 128 + j + 64];
  #pragma unroll
  for (int mf = 0; mf < 4; ++mf) {
    #pragma unroll
    for (int r = 0; r < 4; ++r) {
      int row = mf * 16 + kg * 4 + r;
      int s = s0 + row;
      float ir = irs[row];
      float v0 = acc[mf][0][r] * ir + bias0;
      float v1 = acc[mf][1][r] * ir + bias1;
      float cj = cost[s * HD + j], sj = sint[s * HD + j];
      float cj2 = cost[s * HD + j + 64], sj2 = sint[s * HD + j + 64];
      float* kr = Kraw + row * 132;
      kr[j]      = v0 * cj - v1 * sj;
      kr[j + 64] = v1 * cj2 + v0 * sj2;
    }
  }
  __syncthreads();

  // split + write blob: kv = nh; 2048 slots [ts4][fl4][lane64], hi+lo each
  int kv = nh;
  int kc = sb >> 1, fb = (sb & 1) * 4;
  #pragma unroll
  for (int i = 0; i < 8; ++i) {
    int c = t + i * 256;
    int lc = c & 63, fl = (c >> 6) & 3, ts = (c >> 8) & 3;
    int key = fl * 16 + (lc & 15);
    int d0 = ts * 32 + (lc >> 4) * 8;
    float4 x0 = *(const float4*)(Kraw + key * 132 + d0);
    float4 x1 = *(const float4*)(Kraw + key * 132 + d0 + 4);
    float av[8] = {x0.x, x0.y, x0.z, x0.w, x1.x, x1.y, x1.z, x1.w};
    short hi8[8], lo8[8];
    #pragma unroll
    for (int e = 0; e < 8; ++e) {
      short h = f2bf(av[e]);
      hi8[e] = h;
      lo8[e] = f2bf(av[e] - bf2f(h));
    }
    short* bb = Kblob + (size_t)((l * 2 + kv) * 32 + kc) * 32768
              + (size_t)((ts * 2 + 0) * 8 + fb + fl) * 512 + lc * 8;
    *(short8*)bb = *(short8*)hi8;
    *(short8*)(bb + 4096) = *(short8*)lo8;
  }
}

// ---------------- qgemm: Q = xq . q_w via bf16x3 MFMA, q_w streamed fp32 ----------------
__global__ __launch_bounds__(512) void qgemm_kernel(
    const float* __restrict__ q_w, const short* __restrict__ Ablob,
    float* __restrict__ part) {
  __shared__ __align__(1024) char SM[131072];
  int t = threadIdx.x;
  int nc = blockIdx.x, ks = blockIdx.y, l = blockIdx.z;
  int lane = t & 63, w = t >> 6;
  int fr = lane & 15, kg = lane >> 4;
  const char* abase = (const char*)(Ablob + (size_t)l * 131072 + (size_t)ks * 32768);
  const float* qwl = q_w + (size_t)l * DIM * NQE;

  #pragma unroll
  for (int c = 0; c < 8; ++c) {
    int chunk = w * 8 + c;
    GLOAD16(abase + chunk * 1024 + lane * 16, SM + chunk * 1024);
  }
  #pragma unroll
  for (int c = 0; c < 4; ++c) {
    int r = w * 4 + c;
    GLOAD16((const char*)(qwl + (size_t)(ks * 512 + r) * NQE + nc * 256) + lane * 16,
            SM + 65536 + r * 1024 + lane * 16);
  }
  f32x4 acc[2][2];
  #pragma unroll
  for (int mf = 0; mf < 2; ++mf)
    #pragma unroll
    for (int nf = 0; nf < 2; ++nf) acc[mf][nf] = (f32x4){0.f, 0.f, 0.f, 0.f};
  __syncthreads();

  for (int ts = 0; ts < 16; ++ts) {
    int buf = ts & 1;
    if (ts < 15) {
      #pragma unroll
      for (int c = 0; c < 4; ++c) {
        int r = w * 4 + c;
        GLOAD16((const char*)(qwl + (size_t)(ks * 512 + (ts + 1) * 32 + r) * NQE + nc * 256) + lane * 16,
                SM + 65536 + (buf ^ 1) * 32768 + r * 1024 + lane * 16);
      }
    }
    short8 ah[2], al[2];
    #pragma unroll
    for (int mf = 0; mf < 2; ++mf) {
      ah[mf] = *(const short8*)(SM + ts * 4096 + mf * 1024 + lane * 16);
      al[mf] = *(const short8*)(SM + ts * 4096 + 2048 + mf * 1024 + lane * 16);
    }
    const float* bt = (const float*)(SM + 65536 + buf * 32768);
    #pragma unroll
    for (int nf = 0; nf < 2; ++nf) {
      int c = w * 32 + nf * 16 + fr;
      short bh8[8], bl8[8];
      #pragma unroll
      for (int e = 0; e < 8; ++e) {
        float v = bt[(kg * 8 + e) * 256 + c];
        short h = f2bf(v);
        bh8[e] = h;
        bl8[e] = f2bf(v - bf2f(h));
      }
      short8 bh = *(short8*)bh8, bl = *(short8*)bl8;
      #pragma unroll
      for (int mf = 0; mf < 2; ++mf) {
        acc[mf][nf] = __builtin_amdgcn_mfma_f32_16x16x32_bf16(ah[mf], bh, acc[mf][nf], 0, 0, 0);
        acc[mf][nf] = __builtin_amdgcn_mfma_f32_16x16x32_bf16(ah[mf], bl, acc[mf][nf], 0, 0, 0);
        acc[mf][nf] = __builtin_amdgcn_mfma_f32_16x16x32_bf16(al[mf], bh, acc[mf][nf], 0, 0, 0);
      }
    }
    __syncthreads();
  }

  #pragma unroll
  for (int mf = 0; mf < 2; ++mf) {
    #pragma unroll
    for (int r = 0; r < 4; ++r) {
      int row = mf * 16 + kg * 4 + r;
      float* prow = part + ((size_t)((ks * LYR + l) * NQ + row)) * NQE + nc * 256;
      #pragma unroll
      for (int nf = 0; nf < 2; ++nf) {
        int col = w * 32 + nf * 16 + fr;
        prow[col] = acc[mf][nf][r];
      }
    }
  }
}

// ---------------- qred: sum 4 k-split partials + bias -> Qbuf ----------------
__global__ __launch_bounds__(256) void qred_kernel(
    const float* __restrict__ part, const float* __restrict__ q_b,
    float* __restrict__ Qbuf) {
  int idx = blockIdx.x * 256 + threadIdx.x;
  int n = idx & 2047, q = (idx >> 11) & 31, l = idx >> 16;
  float v = q_b[l * NQE + n];
  #pragma unroll
  for (int ks = 0; ks < 4; ++ks)
    v += part[((size_t)((ks * LYR + l) * NQ + q)) * NQE + n];
  Qbuf[((size_t)l * NQ + q) * NQE + n] = v;
}

// ---------------- qpack: rope Q + split to frag-lane-linear blob ----------------
__global__ __launch_bounds__(256) void qpack_kernel(
    const float* __restrict__ Qbuf, const float* __restrict__ cost,
    const float* __restrict__ sint, const int* __restrict__ q_idx,
    short* __restrict__ Qblob) {
  int kv = blockIdx.x, l = blockIdx.y, t = threadIdx.x;
  short* blob = Qblob + (size_t)(l * 2 + kv) * 65536;
  #pragma unroll
  for (int i = 0; i < 16; ++i) {
    int p = t + i * 256;
    int ts = p >> 10, f = (p >> 6) & 15, lane = p & 63;
    int row = f * 16 + (lane & 15);
    int hh = row >> 5, q = row & 31;
    int h = kv * 8 + hh;
    int d0 = ts * 32 + (lane >> 4) * 8;
    int s = q_idx[q];
    const float* qrow = Qbuf + ((size_t)l * NQ + q) * NQE + h * HD;
    const float* ct = cost + s * HD;
    const float* st = sint + s * HD;
    short hi8[8], lo8[8];
    #pragma unroll
    for (int e = 0; e < 8; ++e) {
      int d = d0 + e;
      float x = qrow[d];
      float xp = qrow[d ^ 64];
      float v = (d < 64) ? (x * ct[d] - xp * st[d]) : (x * ct[d] + xp * st[d]);
      short h2 = f2bf(v);
      hi8[e] = h2;
      lo8[e] = f2bf(v - bf2f(h2));
    }
    *(short8*)(blob + ((ts * 2 + 0) * 16 + f) * 512 + lane * 8) = *(short8*)hi8;
    *(short8*)(blob + ((ts * 2 + 1) * 16 + f) * 512 + lane * 8) = *(short8*)lo8;
  }
}

// ---------------- scores: bf16x3 MFMA, M=256 (8 heads x 32 q) x 128 keys ----------------
__global__ __launch_bounds__(512) void scores_kernel(
    const short* __restrict__ Qblob, const short* __restrict__ Kblob,
    const int* __restrict__ q_idx, float* __restrict__ out) {
  __shared__ short Qs[2][16384];
  __shared__ short Ks[2][8192];
  __shared__ int qiv[32];
  int t = threadIdx.x;
  int kc = blockIdx.x, kv = blockIdx.y, l = blockIdx.z;
  int lane = t & 63, w = t >> 6;
  int wm = w >> 1, wn = w & 1;
  if (t < 32) qiv[t] = q_idx[t];
  const char* qsrc = (const char*)(Qblob + (size_t)(l * 2 + kv) * 65536);
  const char* ksrc = (const char*)(Kblob + (size_t)((l * 2 + kv) * 32 + kc) * 32768);
  #pragma unroll
  for (int c = 0; c < 4; ++c) {
    int off = (w * 4 + c) * 1024;
    GLOAD16(qsrc + off + lane * 16, (char*)Qs[0] + off);
  }
  #pragma unroll
  for (int c = 0; c < 2; ++c) {
    int off = (w * 2 + c) * 1024;
    GLOAD16(ksrc + off + lane * 16, (char*)Ks[0] + off);
  }
  f32x4 acc[4][4];
  #pragma unroll
  for (int mf = 0; mf < 4; ++mf)
    #pragma unroll
    for (int nf = 0; nf < 4; ++nf) acc[mf][nf] = (f32x4){0.f, 0.f, 0.f, 0.f};
  __syncthreads();
  for (int ts = 0; ts < 4; ++ts) {
    int buf = ts & 1;
    if (ts < 3) {
      const char* qs = qsrc + (ts + 1) * 32768;
      const char* ks = ksrc + (ts + 1) * 16384;
      #pragma unroll
      for (int c = 0; c < 4; ++c) {
        int off = (w * 4 + c) * 1024;
        GLOAD16(qs + off + lane * 16, (char*)Qs[(ts + 1) & 1] + off);
      }
      #pragma unroll
      for (int c = 0; c < 2; ++c) {
        int off = (w * 2 + c) * 1024;
        GLOAD16(ks + off + lane * 16, (char*)Ks[(ts + 1) & 1] + off);
      }
    }
    short8 ah[4], al[4];
    #pragma unroll
    for (int mf = 0; mf < 4; ++mf) {
      int f = wm * 4 + mf;
      ah[mf] = *(const short8*)(Qs[buf] + f * 512 + lane * 8);
      al[mf] = *(const short8*)(Qs[buf] + 8192 + f * 512 + lane * 8);
    }
    #pragma unroll
    for (int nf = 0; nf < 4; ++nf) {
      int f = wn * 4 + nf;
      short8 bh = *(const short8*)(Ks[buf] + f * 512 + lane * 8);
      short8 bl = *(const short8*)(Ks[buf] + 4096 + f * 512 + lane * 8);
      #pragma unroll
      for (int mf = 0; mf < 4; ++mf) {
        acc[mf][nf] = __builtin_amdgcn_mfma_f32_16x16x32_bf16(ah[mf], bh, acc[mf][nf], 0, 0, 0);
        acc[mf][nf] = __builtin_amdgcn_mfma_f32_16x16x32_bf16(ah[mf], bl, acc[mf][nf], 0, 0, 0);
        acc[mf][nf] = __builtin_amdgcn_mfma_f32_16x16x32_bf16(al[mf], bh, acc[mf][nf], 0, 0, 0);
      }
    }
    __syncthreads();
  }
  const float scale = 0.088388347648318447f;
  #pragma unroll
  for (int mf = 0; mf < 4; ++mf) {
    #pragma unroll
    for (int r = 0; r < 4; ++r) {
      int rr = wm * 64 + mf * 16 + (lane >> 4) * 4 + r;
      int hh = rr >> 5, q = rr & 31;
      int qv = qiv[q];
      float* orow = out + (((size_t)(l * NH + kv * 8 + hh)) * NQ + q) * SEQ;
      #pragma unroll
      for (int nf = 0; nf < 4; ++nf) {
        int key = kc * 128 + (wn * 4 + nf) * 16 + (lane & 15);
        orow[key] = (key > qv) ? -1e9f : acc[mf][nf][r] * scale;
      }
    }
  }
}

// ---------------- softmax over S ----------------
__global__ __launch_bounds__(256) void softmax_kernel(float* __restrict__ out) {
  size_t row = blockIdx.x;
  float* p = out + row * SEQ;
  int t = threadIdx.x;
  float4 v[4];
  float mx = -1e30f;
  #pragma unroll
  for (int i = 0; i < 4; ++i) {
    v[i] = *(const float4*)(p + t * 4 + i * 1024);
    mx = fmaxf(mx, fmaxf(fmaxf(v[i].x, v[i].y), fmaxf(v[i].z, v[i].w)));
  }
  #pragma unroll
  for (int off = 32; off >= 1; off >>= 1) mx = fmaxf(mx, __shfl_xor(mx, off));
  __shared__ float red[4];
  if ((t & 63) == 0) red[t >> 6] = mx;
  __syncthreads();
  mx = fmaxf(fmaxf(red[0], red[1]), fmaxf(red[2], red[3]));
  __syncthreads();
  float sum = 0.f;
  #pragma unroll
  for (int i = 0; i < 4; ++i) {
    v[i].x = __expf(v[i].x - mx); v[i].y = __expf(v[i].y - mx);
    v[i].z = __expf(v[i].z - mx); v[i].w = __expf(v[i].w - mx);
    sum += v[i].x + v[i].y + v[i].z + v[i].w;
  }
  #pragma unroll
  for (int off = 32; off >= 1; off >>= 1) sum += __shfl_xor(sum, off);
  if ((t & 63) == 0) red[t >> 6] = sum;
  __syncthreads();
  sum = red[0] + red[1] + red[2] + red[3];
  float inv = 1.f / sum;
  #pragma unroll
  for (int i = 0; i < 4; ++i) {
    v[i].x *= inv; v[i].y *= inv; v[i].z *= inv; v[i].w *= inv;
    *(float4*)(p + t * 4 + i * 1024) = v[i];
  }
}

extern "C" void kernel_launch(void* const* d_in, const int* in_sizes, int n_in,
                              void* d_out, int out_size, void* d_ws, size_t ws_size,
                              hipStream_t stream) {
  const float* hs   = (const float*)d_in[0];
  const float* ln_w = (const float*)d_in[1];
  const float* q_w  = (const float*)d_in[2];
  const float* q_b  = (const float*)d_in[3];
  const float* k_w  = (const float*)d_in[4];
  const float* k_b  = (const float*)d_in[5];
  const int* pos    = (const int*)d_in[6];
  const int* qidx   = (const int*)d_in[7];
  float* out = (float*)d_out;
  float* ws = (float*)d_ws;
  float* irq   = ws + WS_IRQ;
  short* Ablob = (short*)(ws + WS_ABLOB);
  float* cost  = ws + WS_COS;
  float* sint  = ws + WS_SIN;
  float* Qbuf  = ws + WS_QBUF;
  float* part  = ws + WS_PART;
  short* W2    = (short*)(ws + WS_W2);
  short* Kblob = (short*)(ws + WS_KBLOB);
  short* Qblob = (short*)(ws + WS_QBLOB);

  prep_kernel<<<dim3(64, LYR), 256, 0, stream>>>(ln_w, k_w, W2);
  rmsq_kernel<<<dim3(NQ, LYR), 256, 0, stream>>>(hs, qidx, irq);
  cossin_kernel<<<(SEQ * HD) / 256, 256, 0, stream>>>(pos, cost, sint);
  xqt_kernel<<<LYR, 256, 0, stream>>>(hs, ln_w, qidx, irq, Ablob);
  kgemm_kernel<<<1024, 256, 0, stream>>>(hs, W2, k_b, cost, sint, Kblob);
  qgemm_kernel<<<dim3(8, 4, LYR), 512, 0, stream>>>(q_w, Ablob, part);
  qred_kernel<<<2048, 256, 0, stream>>>(part, q_b, Qbuf);
  qpack_kernel<<<dim3(2, LYR), 256, 0, stream>>>(Qbuf, cost, sint, qidx, Qblob);
  scores_kernel<<<dim3(32, 2, LYR), 512, 0, stream>>>(Qblob, Kblob, qidx, out);
  softmax_kernel<<<LYR * NH * NQ, 256, 0, stream>>>(out);
}

// Round 10
// 276.791 us; speedup vs baseline: 1.6419x; 1.0341x over previous
//
#include <hip/hip_runtime.h>
#include <hip/hip_bf16.h>
#include <math.h>

#define LYR 8
#define SEQ 4096
#define DIM 2048
#define NH 16
#define HD 128
#define NQ 32
#define NKV 256   // KVH*HD
#define NQE 2048  // H*HD

typedef __attribute__((ext_vector_type(8))) short short8;
typedef __attribute__((ext_vector_type(4))) float f32x4;

// workspace layout (float units)
#define WS_IRQ   0                        // 256
#define WS_ABLOB 256                      // 524288 floats = 1048576 shorts (A-frag blob for Q)
#define WS_COS   524544                   // 524288
#define WS_SIN   1048832                  // 524288
#define WS_QBUF  1573120                  // 524288  summed Q fp32 [l][q][2048]
#define WS_PART  2097408                  // 2097152 partials [ks4][l][q][2048]
#define WS_W2    4194560                  // 4194304 floats = 8388608 shorts (16MB)
#define WS_KBLOB 8388864                  // 8388608 floats = 16777216 shorts (32MB)
#define WS_QBLOB 16777472                 // 524288 floats = 1048576 shorts
// end 17301760 floats ~ 69.2 MB

__device__ __forceinline__ short f2bf(float x) {
  __hip_bfloat16 h = __float2bfloat16(x);
  return *(short*)&h;
}
__device__ __forceinline__ float bf2f(short s) {
  unsigned u = ((unsigned)(unsigned short)s) << 16;
  return __uint_as_float(u);
}

#define GLOAD16(srcp, dstp) \
  __builtin_amdgcn_global_load_lds( \
      (const __attribute__((address_space(1))) unsigned int*)(srcp), \
      (__attribute__((address_space(3))) unsigned int*)(dstp), 16, 0, 0)

// raw barrier: drain LDS ops only; leave global loads in flight across the barrier
#define RBAR() asm volatile("s_waitcnt lgkmcnt(0)\n\ts_barrier" ::: "memory")

// ---------------- prep: W' = ln_w*k_w -> frag-lane-linear bf16 hi/lo blob ----------------
__global__ __launch_bounds__(256) void prep_kernel(
    const float* __restrict__ ln_w, const float* __restrict__ k_w,
    short* __restrict__ W2) {
  int kb = blockIdx.x, l = blockIdx.y, t = threadIdx.x;
  const float* kwl = k_w + (size_t)l * DIM * NKV;
  const float* lnl = ln_w + l * DIM;
  short* blob = W2 + (size_t)(l * 64 + kb) * 16384;
  #pragma unroll
  for (int i = 0; i < 4; ++i) {
    int p = t + i * 256;
    int fi = p >> 6, lane = p & 63;
    int n = fi * 16 + (lane & 15);
    int k0 = kb * 32 + (lane >> 4) * 8;
    short hi8[8], lo8[8];
    #pragma unroll
    for (int e = 0; e < 8; ++e) {
      float v = lnl[k0 + e] * kwl[(size_t)(k0 + e) * NKV + n];
      short h = f2bf(v);
      hi8[e] = h;
      lo8[e] = f2bf(v - bf2f(h));
    }
    *(short8*)(blob + p * 8) = *(short8*)hi8;
    *(short8*)(blob + 8192 + p * 8) = *(short8*)lo8;
  }
}

// ---------------- rmsq: inv_rms for the 32 q rows ----------------
__global__ __launch_bounds__(256) void rmsq_kernel(const float* __restrict__ hs,
                                                   const int* __restrict__ q_idx,
                                                   float* __restrict__ irq) {
  int qi = blockIdx.x, l = blockIdx.y, t = threadIdx.x;
  int s = q_idx[qi];
  const float* row = hs + ((size_t)l * SEQ + s) * DIM;
  float4 v0 = *(const float4*)(row + t * 4);
  float4 v1 = *(const float4*)(row + t * 4 + 1024);
  float acc = v0.x*v0.x + v0.y*v0.y + v0.z*v0.z + v0.w*v0.w
            + v1.x*v1.x + v1.y*v1.y + v1.z*v1.z + v1.w*v1.w;
  #pragma unroll
  for (int off = 32; off >= 1; off >>= 1) acc += __shfl_down(acc, off);
  __shared__ float red[4];
  if ((t & 63) == 0) red[t >> 6] = acc;
  __syncthreads();
  if (t == 0) {
    float tot = red[0] + red[1] + red[2] + red[3];
    irq[l * NQ + qi] = rsqrtf(tot / (float)DIM + 1e-6f);
  }
}

// ---------------- cossin: mrope tables [S][HD] ----------------
__global__ void cossin_kernel(const int* __restrict__ pos_ids,
                              float* __restrict__ cost, float* __restrict__ sint) {
  int idx = blockIdx.x * 256 + threadIdx.x;
  int s = idx >> 7, d = idx & 127;
  int t = (d < 32) ? 0 : (d < 80 ? 1 : 2);
  int j = d & 63;
  double invf = pow(1000000.0, -(double)j / 64.0);
  double ph = (double)pos_ids[t * SEQ + s] * invf;
  cost[idx] = (float)cos(ph);
  sint[idx] = (float)sin(ph);
}

// ---------------- xqt: build A-frag blob for Q proj ----------------
__global__ __launch_bounds__(256) void xqt_kernel(
    const float* __restrict__ hs, const float* __restrict__ ln_w,
    const int* __restrict__ q_idx, const float* __restrict__ irq,
    short* __restrict__ Ablob) {
  __shared__ int qix[32];
  __shared__ float qir[32];
  int l = blockIdx.x, t = threadIdx.x;
  if (t < 32) { qix[t] = q_idx[t]; qir[t] = irq[l * NQ + t]; }
  __syncthreads();
  int lane = t & 63, g4 = t >> 6;
  short* base = Ablob + (size_t)l * 131072;
  int row = lane & 15, kgl = lane >> 4;
  for (int i = 0; i < 64; ++i) {
    int group = g4 * 64 + i;                 // (kb, half, mf)
    int kb = group >> 2, half = (group >> 1) & 1, mf = group & 1;
    int r = row + mf * 16;
    int k0 = kb * 32 + kgl * 8;
    const float* src = hs + ((size_t)l * SEQ + qix[r]) * DIM + k0;
    const float* lnp = ln_w + l * DIM + k0;
    float ir = qir[r];
    float4 v0 = *(const float4*)src;
    float4 v1 = *(const float4*)(src + 4);
    float4 w0 = *(const float4*)lnp;
    float4 w1 = *(const float4*)(lnp + 4);
    float av[8] = {v0.x*w0.x, v0.y*w0.y, v0.z*w0.z, v0.w*w0.w,
                   v1.x*w1.x, v1.y*w1.y, v1.z*w1.z, v1.w*w1.w};
    short o8[8];
    #pragma unroll
    for (int e = 0; e < 8; ++e) {
      float v = av[e] * ir;
      short h = f2bf(v);
      o8[e] = half ? f2bf(v - bf2f(h)) : h;
    }
    *(short8*)(base + group * 512 + lane * 8) = *(short8*)o8;
  }
}

// ---------------- kgemm: K proj bf16x3 MFMA, chunked barriers (1 per 4 K-steps) ----------------
// BM=64 BN=256 BK=32, 256 thr = 4 waves (1m x 4n). A: 2 chunk buffers x 32KB, each
// holding 4 substep images; ONE barrier per chunk (16 total vs 64). B: reg ping-pong
// direct global->VGPR (never needs a barrier; loads stay in flight across RBAR).
__global__ __launch_bounds__(256) void kgemm_kernel(
    const float* __restrict__ hs, const short* __restrict__ W2,
    const float* __restrict__ k_b, const float* __restrict__ cost,
    const float* __restrict__ sint, short* __restrict__ Kblob) {
  __shared__ __align__(1024) char SM[66816];
  // loop: chunk buffers 2 x 32KB at [0,65536); each: 4 substep images x 8KB (hi 4KB, lo 4KB)
  // epilogue overlay: Kraw[64][260] fp32 at [0,66560); irs at [66560,66816)

  int t = threadIdx.x;
  int fid = blockIdx.x;
  int l = fid & 7, sb = fid >> 3;
  int s0 = sb * 64;
  int lane = t & 63, w = t >> 6;
  int fr = lane & 15, kg = lane >> 4;
  int arow = t >> 2, akg = t & 3;

  const float* hrow = hs + ((size_t)l * SEQ + s0 + arow) * DIM + akg * 8;
  const char* wbase = (const char*)(W2 + (size_t)l * 64 * 16384);
  const char* wfrag = wbase + w * 1024 + lane * 16;   // B: nf stride 4096B, lo +16384B, kk stride 32768B

  int awoff = (arow >> 4) * 1024 + (((akg * 16 + (arow & 15)) * 16) ^ (akg << 5));
  int aroff = (lane * 16) ^ ((lane >> 4) << 5);

  f32x4 acc[4][4];
  #pragma unroll
  for (int mf = 0; mf < 4; ++mf)
    #pragma unroll
    for (int nf = 0; nf < 4; ++nf) acc[mf][nf] = (f32x4){0.f, 0.f, 0.f, 0.f};
  float sq = 0.f;
  short8 B0h[4], B0l[4], B1h[4], B1l[4];

  // ---- prologue: stage chunk 0 (substeps 0..3) into buf0; B(kk=0) -> B0 ----
  #pragma unroll
  for (int s = 0; s < 4; ++s) {
    float4 a0 = *(const float4*)(hrow + s * 32);
    float4 a1 = *(const float4*)(hrow + s * 32 + 4);
    float av[8] = {a0.x, a0.y, a0.z, a0.w, a1.x, a1.y, a1.z, a1.w};
    short hi8[8], lo8[8];
    #pragma unroll
    for (int e = 0; e < 8; ++e) {
      sq += av[e] * av[e];
      short h = f2bf(av[e]);
      hi8[e] = h;
      lo8[e] = f2bf(av[e] - bf2f(h));
    }
    *(short8*)(SM + s * 8192 + awoff) = *(short8*)hi8;
    *(short8*)(SM + s * 8192 + 4096 + awoff) = *(short8*)lo8;
  }
  #pragma unroll
  for (int nf = 0; nf < 4; ++nf) {
    B0h[nf] = *(const short8*)(wfrag + nf * 4096);
    B0l[nf] = *(const short8*)(wfrag + nf * 4096 + 16384);
  }
  RBAR();

  for (int ch = 0; ch < 16; ++ch) {
    int buf = ch & 1;
    const char* abuf = SM + buf * 32768;
    char* anext = SM + (buf ^ 1) * 32768;

    // issue next chunk's A loads early (full chunk of cover before use)
    float4 cA[8];
    if (ch < 15) {
      #pragma unroll
      for (int s = 0; s < 4; ++s) {
        cA[s * 2]     = *(const float4*)(hrow + (ch + 1) * 128 + s * 32);
        cA[s * 2 + 1] = *(const float4*)(hrow + (ch + 1) * 128 + s * 32 + 4);
      }
    }

    // 4 barrier-free substeps; B parity is compile-time (s&1)
    #pragma unroll
    for (int s = 0; s < 4; ++s) {
      // prefetch B for kk+1 into the alternate reg set
      if (s < 3 || ch < 15) {
        const char* bsrc = wfrag + (size_t)(ch * 4 + s + 1) * 32768;
        if ((s & 1) == 0) {
          #pragma unroll
          for (int nf = 0; nf < 4; ++nf) {
            B1h[nf] = *(const short8*)(bsrc + nf * 4096);
            B1l[nf] = *(const short8*)(bsrc + nf * 4096 + 16384);
          }
        } else {
          #pragma unroll
          for (int nf = 0; nf < 4; ++nf) {
            B0h[nf] = *(const short8*)(bsrc + nf * 4096);
            B0l[nf] = *(const short8*)(bsrc + nf * 4096 + 16384);
          }
        }
      }
      short8 ah[4], al[4];
      #pragma unroll
      for (int mf = 0; mf < 4; ++mf) {
        ah[mf] = *(const short8*)(abuf + s * 8192 + mf * 1024 + aroff);
        al[mf] = *(const short8*)(abuf + s * 8192 + 4096 + mf * 1024 + aroff);
      }
      __builtin_amdgcn_s_setprio(1);
      if ((s & 1) == 0) {
        #pragma unroll
        for (int nf = 0; nf < 4; ++nf) {
          #pragma unroll
          for (int mf = 0; mf < 4; ++mf) {
            acc[mf][nf] = __builtin_amdgcn_mfma_f32_16x16x32_bf16(ah[mf], B0h[nf], acc[mf][nf], 0, 0, 0);
            acc[mf][nf] = __builtin_amdgcn_mfma_f32_16x16x32_bf16(ah[mf], B0l[nf], acc[mf][nf], 0, 0, 0);
            acc[mf][nf] = __builtin_amdgcn_mfma_f32_16x16x32_bf16(al[mf], B0h[nf], acc[mf][nf], 0, 0, 0);
          }
        }
      } else {
        #pragma unroll
        for (int nf = 0; nf < 4; ++nf) {
          #pragma unroll
          for (int mf = 0; mf < 4; ++mf) {
            acc[mf][nf] = __builtin_amdgcn_mfma_f32_16x16x32_bf16(ah[mf], B1h[nf], acc[mf][nf], 0, 0, 0);
            acc[mf][nf] = __builtin_amdgcn_mfma_f32_16x16x32_bf16(ah[mf], B1l[nf], acc[mf][nf], 0, 0, 0);
            acc[mf][nf] = __builtin_amdgcn_mfma_f32_16x16x32_bf16(al[mf], B1h[nf], acc[mf][nf], 0, 0, 0);
          }
        }
      }
      __builtin_amdgcn_s_setprio(0);
    }

    // stage chunk ch+1 into the other buffer (loads had ~full-chunk cover)
    if (ch < 15) {
      #pragma unroll
      for (int s = 0; s < 4; ++s) {
        float4 a0 = cA[s * 2];
        float4 a1 = cA[s * 2 + 1];
        float av[8] = {a0.x, a0.y, a0.z, a0.w, a1.x, a1.y, a1.z, a1.w};
        short hi8[8], lo8[8];
        #pragma unroll
        for (int e = 0; e < 8; ++e) {
          sq += av[e] * av[e];
          short h = f2bf(av[e]);
          hi8[e] = h;
          lo8[e] = f2bf(av[e] - bf2f(h));
        }
        *(short8*)(anext + s * 8192 + awoff) = *(short8*)hi8;
        *(short8*)(anext + s * 8192 + 4096 + awoff) = *(short8*)lo8;
      }
    }
    RBAR();
  }

  // ---- epilogue ----
  sq += __shfl_xor(sq, 1);
  sq += __shfl_xor(sq, 2);
  float* irs = (float*)(SM + 66560);
  if ((t & 3) == 0) irs[arow] = rsqrtf(sq / (float)DIM + 1e-6f);
  __syncthreads();

  float* Kraw = (float*)SM;
  int j = w * 16 + fr;
  float bias0 = k_b[l * NKV + j];
  float bias1 = k_b[l * NKV + j + 64];
  float bias2 = k_b[l * NKV + j + 128];
  float bias3 = k_b[l * NKV + j + 192];
  #pragma unroll
  for (int mf = 0; mf < 4; ++mf) {
    #pragma unroll
    for (int r = 0; r < 4; ++r) {
      int row = mf * 16 + kg * 4 + r;
      int s = s0 + row;
      float ir = irs[row];
      float v0 = acc[mf][0][r] * ir + bias0;
      float v1 = acc[mf][1][r] * ir + bias1;
      float v2 = acc[mf][2][r] * ir + bias2;
      float v3 = acc[mf][3][r] * ir + bias3;
      float cj = cost[s * HD + j], sj = sint[s * HD + j];
      float cj2 = cost[s * HD + j + 64], sj2 = sint[s * HD + j + 64];
      float* kr = Kraw + row * 260;
      kr[j]       = v0 * cj - v1 * sj;
      kr[j + 64]  = v1 * cj2 + v0 * sj2;
      kr[j + 128] = v2 * cj - v3 * sj;
      kr[j + 192] = v3 * cj2 + v2 * sj2;
    }
  }
  __syncthreads();

  int kc = sb >> 1, fb = (sb & 1) * 4;
  #pragma unroll
  for (int i = 0; i < 8; ++i) {
    int c = t + i * 256;
    int lc = c & 63, fl = (c >> 6) & 3, ts = (c >> 8) & 3, kv = c >> 10;
    int key = fl * 16 + (lc & 15);
    int d0 = kv * 128 + ts * 32 + (lc >> 4) * 8;
    float4 x0 = *(const float4*)(Kraw + key * 260 + d0);
    float4 x1 = *(const float4*)(Kraw + key * 260 + d0 + 4);
    float av[8] = {x0.x, x0.y, x0.z, x0.w, x1.x, x1.y, x1.z, x1.w};
    short hi8[8], lo8[8];
    #pragma unroll
    for (int e = 0; e < 8; ++e) {
      short h = f2bf(av[e]);
      hi8[e] = h;
      lo8[e] = f2bf(av[e] - bf2f(h));
    }
    short* bb = Kblob + (size_t)((l * 2 + kv) * 32 + kc) * 32768
              + (size_t)((ts * 2 + 0) * 8 + fb + fl) * 512 + lc * 8;
    *(short8*)bb = *(short8*)hi8;
    *(short8*)(bb + 4096) = *(short8*)lo8;
  }
}

// ---------------- qgemm: Q = xq . q_w via bf16x3 MFMA, q_w streamed fp32 ----------------
__global__ __launch_bounds__(512) void qgemm_kernel(
    const float* __restrict__ q_w, const short* __restrict__ Ablob,
    float* __restrict__ part) {
  __shared__ __align__(1024) char SM[131072];
  int t = threadIdx.x;
  int nc = blockIdx.x, ks = blockIdx.y, l = blockIdx.z;
  int lane = t & 63, w = t >> 6;
  int fr = lane & 15, kg = lane >> 4;
  const char* abase = (const char*)(Ablob + (size_t)l * 131072 + (size_t)ks * 32768);
  const float* qwl = q_w + (size_t)l * DIM * NQE;

  #pragma unroll
  for (int c = 0; c < 8; ++c) {
    int chunk = w * 8 + c;
    GLOAD16(abase + chunk * 1024 + lane * 16, SM + chunk * 1024);
  }
  #pragma unroll
  for (int c = 0; c < 4; ++c) {
    int r = w * 4 + c;
    GLOAD16((const char*)(qwl + (size_t)(ks * 512 + r) * NQE + nc * 256) + lane * 16,
            SM + 65536 + r * 1024 + lane * 16);
  }
  f32x4 acc[2][2];
  #pragma unroll
  for (int mf = 0; mf < 2; ++mf)
    #pragma unroll
    for (int nf = 0; nf < 2; ++nf) acc[mf][nf] = (f32x4){0.f, 0.f, 0.f, 0.f};
  __syncthreads();

  for (int ts = 0; ts < 16; ++ts) {
    int buf = ts & 1;
    if (ts < 15) {
      #pragma unroll
      for (int c = 0; c < 4; ++c) {
        int r = w * 4 + c;
        GLOAD16((const char*)(qwl + (size_t)(ks * 512 + (ts + 1) * 32 + r) * NQE + nc * 256) + lane * 16,
                SM + 65536 + (buf ^ 1) * 32768 + r * 1024 + lane * 16);
      }
    }
    short8 ah[2], al[2];
    #pragma unroll
    for (int mf = 0; mf < 2; ++mf) {
      ah[mf] = *(const short8*)(SM + ts * 4096 + mf * 1024 + lane * 16);
      al[mf] = *(const short8*)(SM + ts * 4096 + 2048 + mf * 1024 + lane * 16);
    }
    const float* bt = (const float*)(SM + 65536 + buf * 32768);
    #pragma unroll
    for (int nf = 0; nf < 2; ++nf) {
      int c = w * 32 + nf * 16 + fr;
      short bh8[8], bl8[8];
      #pragma unroll
      for (int e = 0; e < 8; ++e) {
        float v = bt[(kg * 8 + e) * 256 + c];
        short h = f2bf(v);
        bh8[e] = h;
        bl8[e] = f2bf(v - bf2f(h));
      }
      short8 bh = *(short8*)bh8, bl = *(short8*)bl8;
      #pragma unroll
      for (int mf = 0; mf < 2; ++mf) {
        acc[mf][nf] = __builtin_amdgcn_mfma_f32_16x16x32_bf16(ah[mf], bh, acc[mf][nf], 0, 0, 0);
        acc[mf][nf] = __builtin_amdgcn_mfma_f32_16x16x32_bf16(ah[mf], bl, acc[mf][nf], 0, 0, 0);
        acc[mf][nf] = __builtin_amdgcn_mfma_f32_16x16x32_bf16(al[mf], bh, acc[mf][nf], 0, 0, 0);
      }
    }
    __syncthreads();
  }

  #pragma unroll
  for (int mf = 0; mf < 2; ++mf) {
    #pragma unroll
    for (int r = 0; r < 4; ++r) {
      int row = mf * 16 + kg * 4 + r;
      float* prow = part + ((size_t)((ks * LYR + l) * NQ + row)) * NQE + nc * 256;
      #pragma unroll
      for (int nf = 0; nf < 2; ++nf) {
        int col = w * 32 + nf * 16 + fr;
        prow[col] = acc[mf][nf][r];
      }
    }
  }
}

// ---------------- qred: sum 4 k-split partials + bias -> Qbuf ----------------
__global__ __launch_bounds__(256) void qred_kernel(
    const float* __restrict__ part, const float* __restrict__ q_b,
    float* __restrict__ Qbuf) {
  int idx = blockIdx.x * 256 + threadIdx.x;
  int n = idx & 2047, q = (idx >> 11) & 31, l = idx >> 16;
  float v = q_b[l * NQE + n];
  #pragma unroll
  for (int ks = 0; ks < 4; ++ks)
    v += part[((size_t)((ks * LYR + l) * NQ + q)) * NQE + n];
  Qbuf[((size_t)l * NQ + q) * NQE + n] = v;
}

// ---------------- qpack: rope Q + split to frag-lane-linear blob ----------------
__global__ __launch_bounds__(256) void qpack_kernel(
    const float* __restrict__ Qbuf, const float* __restrict__ cost,
    const float* __restrict__ sint, const int* __restrict__ q_idx,
    short* __restrict__ Qblob) {
  int kv = blockIdx.x, l = blockIdx.y, t = threadIdx.x;
  short* blob = Qblob + (size_t)(l * 2 + kv) * 65536;
  #pragma unroll
  for (int i = 0; i < 16; ++i) {
    int p = t + i * 256;
    int ts = p >> 10, f = (p >> 6) & 15, lane = p & 63;
    int row = f * 16 + (lane & 15);
    int hh = row >> 5, q = row & 31;
    int h = kv * 8 + hh;
    int d0 = ts * 32 + (lane >> 4) * 8;
    int s = q_idx[q];
    const float* qrow = Qbuf + ((size_t)l * NQ + q) * NQE + h * HD;
    const float* ct = cost + s * HD;
    const float* st = sint + s * HD;
    short hi8[8], lo8[8];
    #pragma unroll
    for (int e = 0; e < 8; ++e) {
      int d = d0 + e;
      float x = qrow[d];
      float xp = qrow[d ^ 64];
      float v = (d < 64) ? (x * ct[d] - xp * st[d]) : (x * ct[d] + xp * st[d]);
      short h2 = f2bf(v);
      hi8[e] = h2;
      lo8[e] = f2bf(v - bf2f(h2));
    }
    *(short8*)(blob + ((ts * 2 + 0) * 16 + f) * 512 + lane * 8) = *(short8*)hi8;
    *(short8*)(blob + ((ts * 2 + 1) * 16 + f) * 512 + lane * 8) = *(short8*)lo8;
  }
}

// ---------------- scores: bf16x3 MFMA, M=256 (8 heads x 32 q) x 128 keys ----------------
__global__ __launch_bounds__(512) void scores_kernel(
    const short* __restrict__ Qblob, const short* __restrict__ Kblob,
    const int* __restrict__ q_idx, float* __restrict__ out) {
  __shared__ short Qs[2][16384];
  __shared__ short Ks[2][8192];
  __shared__ int qiv[32];
  int t = threadIdx.x;
  int kc = blockIdx.x, kv = blockIdx.y, l = blockIdx.z;
  int lane = t & 63, w = t >> 6;
  int wm = w >> 1, wn = w & 1;
  if (t < 32) qiv[t] = q_idx[t];
  const char* qsrc = (const char*)(Qblob + (size_t)(l * 2 + kv) * 65536);
  const char* ksrc = (const char*)(Kblob + (size_t)((l * 2 + kv) * 32 + kc) * 32768);
  #pragma unroll
  for (int c = 0; c < 4; ++c) {
    int off = (w * 4 + c) * 1024;
    GLOAD16(qsrc + off + lane * 16, (char*)Qs[0] + off);
  }
  #pragma unroll
  for (int c = 0; c < 2; ++c) {
    int off = (w * 2 + c) * 1024;
    GLOAD16(ksrc + off + lane * 16, (char*)Ks[0] + off);
  }
  f32x4 acc[4][4];
  #pragma unroll
  for (int mf = 0; mf < 4; ++mf)
    #pragma unroll
    for (int nf = 0; nf < 4; ++nf) acc[mf][nf] = (f32x4){0.f, 0.f, 0.f, 0.f};
  __syncthreads();
  for (int ts = 0; ts < 4; ++ts) {
    int buf = ts & 1;
    if (ts < 3) {
      const char* qs = qsrc + (ts + 1) * 32768;
      const char* ks = ksrc + (ts + 1) * 16384;
      #pragma unroll
      for (int c = 0; c < 4; ++c) {
        int off = (w * 4 + c) * 1024;
        GLOAD16(qs + off + lane * 16, (char*)Qs[(ts + 1) & 1] + off);
      }
      #pragma unroll
      for (int c = 0; c < 2; ++c) {
        int off = (w * 2 + c) * 1024;
        GLOAD16(ks + off + lane * 16, (char*)Ks[(ts + 1) & 1] + off);
      }
    }
    short8 ah[4], al[4];
    #pragma unroll
    for (int mf = 0; mf < 4; ++mf) {
      int f = wm * 4 + mf;
      ah[mf] = *(const short8*)(Qs[buf] + f * 512 + lane * 8);
      al[mf] = *(const short8*)(Qs[buf] + 8192 + f * 512 + lane * 8);
    }
    #pragma unroll
    for (int nf = 0; nf < 4; ++nf) {
      int f = wn * 4 + nf;
      short8 bh = *(const short8*)(Ks[buf] + f * 512 + lane * 8);
      short8 bl = *(const short8*)(Ks[buf] + 4096 + f * 512 + lane * 8);
      #pragma unroll
      for (int mf = 0; mf < 4; ++mf) {
        acc[mf][nf] = __builtin_amdgcn_mfma_f32_16x16x32_bf16(ah[mf], bh, acc[mf][nf], 0, 0, 0);
        acc[mf][nf] = __builtin_amdgcn_mfma_f32_16x16x32_bf16(ah[mf], bl, acc[mf][nf], 0, 0, 0);
        acc[mf][nf] = __builtin_amdgcn_mfma_f32_16x16x32_bf16(al[mf], bh, acc[mf][nf], 0, 0, 0);
      }
    }
    __syncthreads();
  }
  const float scale = 0.088388347648318447f;
  #pragma unroll
  for (int mf = 0; mf < 4; ++mf) {
    #pragma unroll
    for (int r = 0; r < 4; ++r) {
      int rr = wm * 64 + mf * 16 + (lane >> 4) * 4 + r;
      int hh = rr >> 5, q = rr & 31;
      int qv = qiv[q];
      float* orow = out + (((size_t)(l * NH + kv * 8 + hh)) * NQ + q) * SEQ;
      #pragma unroll
      for (int nf = 0; nf < 4; ++nf) {
        int key = kc * 128 + (wn * 4 + nf) * 16 + (lane & 15);
        orow[key] = (key > qv) ? -1e9f : acc[mf][nf][r] * scale;
      }
    }
  }
}

// ---------------- softmax over S ----------------
__global__ __launch_bounds__(256) void softmax_kernel(float* __restrict__ out) {
  size_t row = blockIdx.x;
  float* p = out + row * SEQ;
  int t = threadIdx.x;
  float4 v[4];
  float mx = -1e30f;
  #pragma unroll
  for (int i = 0; i < 4; ++i) {
    v[i] = *(const float4*)(p + t * 4 + i * 1024);
    mx = fmaxf(mx, fmaxf(fmaxf(v[i].x, v[i].y), fmaxf(v[i].z, v[i].w)));
  }
  #pragma unroll
  for (int off = 32; off >= 1; off >>= 1) mx = fmaxf(mx, __shfl_xor(mx, off));
  __shared__ float red[4];
  if ((t & 63) == 0) red[t >> 6] = mx;
  __syncthreads();
  mx = fmaxf(fmaxf(red[0], red[1]), fmaxf(red[2], red[3]));
  __syncthreads();
  float sum = 0.f;
  #pragma unroll
  for (int i = 0; i < 4; ++i) {
    v[i].x = __expf(v[i].x - mx); v[i].y = __expf(v[i].y - mx);
    v[i].z = __expf(v[i].z - mx); v[i].w = __expf(v[i].w - mx);
    sum += v[i].x + v[i].y + v[i].z + v[i].w;
  }
  #pragma unroll
  for (int off = 32; off >= 1; off >>= 1) sum += __shfl_xor(sum, off);
  if ((t & 63) == 0) red[t >> 6] = sum;
  __syncthreads();
  sum = red[0] + red[1] + red[2] + red[3];
  float inv = 1.f / sum;
  #pragma unroll
  for (int i = 0; i < 4; ++i) {
    v[i].x *= inv; v[i].y *= inv; v[i].z *= inv; v[i].w *= inv;
    *(float4*)(p + t * 4 + i * 1024) = v[i];
  }
}

extern "C" void kernel_launch(void* const* d_in, const int* in_sizes, int n_in,
                              void* d_out, int out_size, void* d_ws, size_t ws_size,
                              hipStream_t stream) {
  const float* hs   = (const float*)d_in[0];
  const float* ln_w = (const float*)d_in[1];
  const float* q_w  = (const float*)d_in[2];
  const float* q_b  = (const float*)d_in[3];
  const float* k_w  = (const float*)d_in[4];
  const float* k_b  = (const float*)d_in[5];
  const int* pos    = (const int*)d_in[6];
  const int* qidx   = (const int*)d_in[7];
  float* out = (float*)d_out;
  float* ws = (float*)d_ws;
  float* irq   = ws + WS_IRQ;
  short* Ablob = (short*)(ws + WS_ABLOB);
  float* cost  = ws + WS_COS;
  float* sint  = ws + WS_SIN;
  float* Qbuf  = ws + WS_QBUF;
  float* part  = ws + WS_PART;
  short* W2    = (short*)(ws + WS_W2);
  short* Kblob = (short*)(ws + WS_KBLOB);
  short* Qblob = (short*)(ws + WS_QBLOB);

  prep_kernel<<<dim3(64, LYR), 256, 0, stream>>>(ln_w, k_w, W2);
  rmsq_kernel<<<dim3(NQ, LYR), 256, 0, stream>>>(hs, qidx, irq);
  cossin_kernel<<<(SEQ * HD) / 256, 256, 0, stream>>>(pos, cost, sint);
  xqt_kernel<<<LYR, 256, 0, stream>>>(hs, ln_w, qidx, irq, Ablob);
  kgemm_kernel<<<512, 256, 0, stream>>>(hs, W2, k_b, cost, sint, Kblob);
  qgemm_kernel<<<dim3(8, 4, LYR), 512, 0, stream>>>(q_w, Ablob, part);
  qred_kernel<<<2048, 256, 0, stream>>>(part, q_b, Qbuf);
  qpack_kernel<<<dim3(2, LYR), 256, 0, stream>>>(Qbuf, cost, sint, qidx, Qblob);
  scores_kernel<<<dim3(32, 2, LYR), 512, 0, stream>>>(Qblob, Kblob, qidx, out);
  softmax_kernel<<<LYR * NH * NQ, 256, 0, stream>>>(out);
}